// Round 2
// baseline (4596.731 us; speedup 1.0000x reference)
//
#include <hip/hip_runtime.h>
#include <math.h>

#define E_EDGES 100000

// ---------------- structs passed by value as kernargs ----------------
struct CsrArgs { int nslots; int relid[18]; int nd[18]; int cntoff[18]; int rpoff[18]; };

struct ConvArgs {
  const float* xsrc[6];
  const int*   rowptr[6];
  const int*   epack[6];   // (dst<<16)|src, CSR order
  const float* wl[6];
  const float* xdst;
  const float* wrsum;
  const float* blsum;
  float*       out;
  int nrels;
  int nd;
};

struct WsumArgs { int nrels[5]; int relid[5][6]; };

// ---------------- generic fp32 GEMM: C = op(A[M,K] @ W[K,N] + b) ----------------
__global__ __launch_bounds__(256) void gemm_kernel(
    const float* __restrict__ A, const float* __restrict__ W,
    const float* __restrict__ bias, float* __restrict__ C,
    int M, int K, int N, int relu)
{
  __shared__ float sA[64][36];
  const int tid = threadIdx.x;
  const int tx = tid & 31, ty = tid >> 5;
  const int rowbase = blockIdx.x * 64;
  const int colbase = blockIdx.y * 128;
  float acc[8][4];
  #pragma unroll
  for (int i = 0; i < 8; i++)
    #pragma unroll
    for (int j = 0; j < 4; j++) acc[i][j] = 0.f;

  for (int k0 = 0; k0 < K; k0 += 32) {
    #pragma unroll
    for (int i = 0; i < 8; i++) {
      int flat = tid + i * 256;
      int kk = flat & 31, r = flat >> 5;
      int gr = rowbase + r, gk = k0 + kk;
      sA[r][kk] = (gr < M && gk < K) ? A[(long)gr * K + gk] : 0.f;
    }
    __syncthreads();
    #pragma unroll 8
    for (int kk = 0; kk < 32; kk++) {
      float4 wv = make_float4(0.f, 0.f, 0.f, 0.f);
      if (k0 + kk < K) wv = *(const float4*)&W[(long)(k0 + kk) * N + colbase + tx * 4];
      #pragma unroll
      for (int i = 0; i < 8; i++) {
        float av = sA[ty * 8 + i][kk];
        acc[i][0] += av * wv.x; acc[i][1] += av * wv.y;
        acc[i][2] += av * wv.z; acc[i][3] += av * wv.w;
      }
    }
    __syncthreads();
  }
  float4 bv = make_float4(0.f, 0.f, 0.f, 0.f);
  if (bias) bv = *(const float4*)&bias[colbase + tx * 4];
  #pragma unroll
  for (int i = 0; i < 8; i++) {
    int gr = rowbase + ty * 8 + i;
    if (gr < M) {
      float4 o;
      o.x = acc[i][0] + bv.x; o.y = acc[i][1] + bv.y;
      o.z = acc[i][2] + bv.z; o.w = acc[i][3] + bv.w;
      if (relu) { o.x = fmaxf(o.x, 0.f); o.y = fmaxf(o.y, 0.f); o.z = fmaxf(o.z, 0.f); o.w = fmaxf(o.w, 0.f); }
      *(float4*)&C[(long)gr * N + colbase + tx * 4] = o;
    }
  }
}

// ---------------- CSR build ----------------
__global__ __launch_bounds__(256) void hist_kernel(const int* __restrict__ edges,
                                                   int* __restrict__ cnt, CsrArgs a)
{
  int slot = blockIdx.y;
  int e = blockIdx.x * 256 + threadIdx.x;
  if (e >= E_EDGES) return;
  int r = a.relid[slot];
  int dst = edges[(r * 2 + 1) * E_EDGES + e];
  atomicAdd(&cnt[a.cntoff[slot] + dst], 1);
}

__global__ __launch_bounds__(256) void scan_kernel(const int* __restrict__ cnt,
                                                   int* __restrict__ rowptr, CsrArgs a)
{
  __shared__ int sbuf[256];
  int slot = blockIdx.x;
  int n = a.nd[slot], cb = a.cntoff[slot], rb = a.rpoff[slot];
  int tid = threadIdx.x;
  int carry = 0;
  for (int c0 = 0; c0 < n; c0 += 256) {
    int i = c0 + tid;
    int v = (i < n) ? cnt[cb + i] : 0;
    sbuf[tid] = v;
    __syncthreads();
    #pragma unroll
    for (int off = 1; off < 256; off <<= 1) {
      int t = (tid >= off) ? sbuf[tid - off] : 0;
      __syncthreads();
      sbuf[tid] += t;
      __syncthreads();
    }
    if (i < n) rowptr[rb + i] = carry + sbuf[tid] - v;
    carry += sbuf[255];
    __syncthreads();
  }
  if (tid == 0) rowptr[rb + n] = carry;
}

__global__ __launch_bounds__(256) void scatter_kernel(const int* __restrict__ edges,
                                                      int* __restrict__ cursor,
                                                      int* __restrict__ epack, CsrArgs a)
{
  int slot = blockIdx.y;
  int e = blockIdx.x * 256 + threadIdx.x;
  if (e >= E_EDGES) return;
  int r = a.relid[slot];
  int src = edges[r * 2 * E_EDGES + e];
  int dst = edges[(r * 2 + 1) * E_EDGES + e];
  int pos = atomicAdd(&cursor[a.rpoff[slot] + dst], 1);
  epack[slot * E_EDGES + pos] = (dst << 16) | src;   // src<=25000<2^16, dst<2^15
}

// ---------------- wr / bl sums per dst-type group ----------------
__global__ __launch_bounds__(256) void wrsum_kernel(const float* __restrict__ wr,
                                                    const float* __restrict__ bl,
                                                    float* __restrict__ wrsum,
                                                    float* __restrict__ blsum, WsumArgs a)
{
  int g = blockIdx.x >> 6;
  int chunk = blockIdx.x & 63;
  int idx = chunk * 256 + threadIdx.x;
  float s = 0.f;
  for (int i = 0; i < a.nrels[g]; i++) s += wr[(long)a.relid[g][i] * 16384 + idx];
  wrsum[(long)g * 16384 + idx] = s;
  if (chunk == 0 && threadIdx.x < 128) {
    float b = 0.f;
    for (int i = 0; i < a.nrels[g]; i++) b += bl[a.relid[g][i] * 128 + threadIdx.x];
    blsum[g * 128 + threadIdx.x] = b;
  }
}

// ---------------- fused hetero-conv for one dst type ----------------
// Edge-parallel aggregation: 8 edges per block-iter (32 lanes x float4 each),
// unrolled x2 -> 16 gathers in flight, LDS fp32 atomics into the 64x128 tile.
__global__ __launch_bounds__(256) void conv_kernel(ConvArgs a)
{
  __shared__ float sm[64 * 128];
  const int tid = threadIdx.x;
  const int tx = tid & 31, ty = tid >> 5;   // ty: 0..7 (edge slot / GEMM row group)
  const int f4 = tx * 4;
  const int rowbase = blockIdx.x * 64;
  const int nr = tid >> 2, nfo = (tid & 3) * 32;  // normalize mapping: row, feat offset
  float acc[8][4];
  #pragma unroll
  for (int i = 0; i < 8; i++)
    #pragma unroll
    for (int j = 0; j < 4; j++) acc[i][j] = 0.f;

  for (int rel = 0; rel <= a.nrels; rel++) {
    if (rel < a.nrels) {
      // zero the tile
      #pragma unroll
      for (int i = 0; i < 8; i++)
        *(float4*)&sm[(i * 256 + tid) * 4] = make_float4(0.f, 0.f, 0.f, 0.f);
      __syncthreads();

      const int* rp = a.rowptr[rel];
      const int* ep = a.epack[rel];
      const float* xs = a.xsrc[rel];
      int rend = rowbase + 64; if (rend > a.nd) rend = a.nd;
      int e0 = rp[rowbase];
      int e1 = rp[rend];

      int e = e0 + ty;
      for (; e + 8 < e1; e += 16) {
        int p0 = ep[e];
        int p1 = ep[e + 8];
        float4 v0 = *(const float4*)&xs[(long)(p0 & 0xFFFF) * 128 + f4];
        float4 v1 = *(const float4*)&xs[(long)(p1 & 0xFFFF) * 128 + f4];
        float* d0 = &sm[((p0 >> 16) - rowbase) * 128 + f4];
        float* d1 = &sm[((p1 >> 16) - rowbase) * 128 + f4];
        atomicAdd(d0 + 0, v0.x); atomicAdd(d0 + 1, v0.y);
        atomicAdd(d0 + 2, v0.z); atomicAdd(d0 + 3, v0.w);
        atomicAdd(d1 + 0, v1.x); atomicAdd(d1 + 1, v1.y);
        atomicAdd(d1 + 2, v1.z); atomicAdd(d1 + 3, v1.w);
      }
      for (; e < e1; e += 8) {
        int p = ep[e];
        float4 v = *(const float4*)&xs[(long)(p & 0xFFFF) * 128 + f4];
        float* d = &sm[((p >> 16) - rowbase) * 128 + f4];
        atomicAdd(d + 0, v.x); atomicAdd(d + 1, v.y);
        atomicAdd(d + 2, v.z); atomicAdd(d + 3, v.w);
      }
      __syncthreads();

      // normalize: mean = sum / max(cnt,1)
      if (rowbase + nr < a.nd) {
        int c = rp[rowbase + nr + 1] - rp[rowbase + nr];
        float inv = 1.0f / (float)(c > 1 ? c : 1);
        #pragma unroll
        for (int j = 0; j < 8; j++) {
          float4 v = *(float4*)&sm[nr * 128 + nfo + j * 4];
          v.x *= inv; v.y *= inv; v.z *= inv; v.w *= inv;
          *(float4*)&sm[nr * 128 + nfo + j * 4] = v;
        }
      }
      __syncthreads();
    } else {
      // final pass: xdst tile
      #pragma unroll
      for (int j = 0; j < 8; j++) {
        float4 v = make_float4(0.f, 0.f, 0.f, 0.f);
        if (rowbase + nr < a.nd)
          v = *(const float4*)&a.xdst[(long)(rowbase + nr) * 128 + nfo + j * 4];
        *(float4*)&sm[nr * 128 + nfo + j * 4] = v;
      }
      __syncthreads();
    }

    // GEMM accumulate: acc += sm @ w
    const float* w = (rel < a.nrels) ? a.wl[rel] : a.wrsum;
    for (int k = 0; k < 128; k += 4) {
      float4 w0 = *(const float4*)&w[(k + 0) * 128 + tx * 4];
      float4 w1 = *(const float4*)&w[(k + 1) * 128 + tx * 4];
      float4 w2 = *(const float4*)&w[(k + 2) * 128 + tx * 4];
      float4 w3 = *(const float4*)&w[(k + 3) * 128 + tx * 4];
      #pragma unroll
      for (int i = 0; i < 8; i++) {
        float4 av = *(const float4*)&sm[(ty * 8 + i) * 128 + k];
        acc[i][0] += av.x * w0.x + av.y * w1.x + av.z * w2.x + av.w * w3.x;
        acc[i][1] += av.x * w0.y + av.y * w1.y + av.z * w2.y + av.w * w3.y;
        acc[i][2] += av.x * w0.z + av.y * w1.z + av.z * w2.z + av.w * w3.z;
        acc[i][3] += av.x * w0.w + av.y * w1.w + av.z * w2.w + av.w * w3.w;
      }
    }
    __syncthreads();
  }

  float4 bv = *(const float4*)&a.blsum[tx * 4];
  #pragma unroll
  for (int i = 0; i < 8; i++) {
    int gr = rowbase + ty * 8 + i;
    if (gr < a.nd) {
      float4 o;
      o.x = acc[i][0] + bv.x; o.y = acc[i][1] + bv.y;
      o.z = acc[i][2] + bv.z; o.w = acc[i][3] + bv.w;
      *(float4*)&a.out[(long)gr * 128 + tx * 4] = o;
    }
  }
}

// ---------------- cross-layer ID-matched scatter (binary search) ----------------
__global__ __launch_bounds__(128) void xscatter_kernel(const int* __restrict__ map0,
                                                       const int* __restrict__ map1,
                                                       const float* __restrict__ src,
                                                       float* __restrict__ dst, int n)
{
  __shared__ int spos;
  int j = blockIdx.x;
  if (threadIdx.x == 0) {
    int key = map1[j];
    int lo = 0, hi = n - 1, pos = -1;
    while (lo <= hi) {
      int mid = (lo + hi) >> 1;
      int v = map0[mid];
      if (v == key) { pos = mid; break; }
      if (v < key) lo = mid + 1; else hi = mid - 1;
    }
    spos = pos;
  }
  __syncthreads();
  int p = spos;
  if (p >= 0) dst[(long)j * 128 + threadIdx.x] = src[(long)p * 128 + threadIdx.x];
}

// ---------------- head: out[row*2+col] = post(hid[row,:256] . w2 + b2) ----------------
__global__ __launch_bounds__(64) void head_reduce_kernel(const float* __restrict__ hid,
                                                         const float* __restrict__ w2,
                                                         const float* __restrict__ b2,
                                                         float* __restrict__ out,
                                                         int col, int dosig)
{
  int row = blockIdx.x;
  int lane = threadIdx.x;
  const float* h = hid + (long)row * 256;
  float s = h[lane] * w2[lane] + h[lane + 64] * w2[lane + 64]
          + h[lane + 128] * w2[lane + 128] + h[lane + 192] * w2[lane + 192];
  #pragma unroll
  for (int off = 32; off >= 1; off >>= 1) s += __shfl_down(s, off, 64);
  if (lane == 0) {
    float v = s + b2[0];
    if (dosig) v = 1.0f / (1.0f + expf(-v));
    out[row * 2 + col] = v;
  }
}

// ---------------- host orchestration ----------------
extern "C" void kernel_launch(void* const* d_in, const int* in_sizes, int n_in,
                              void* d_out, int out_size, void* d_ws, size_t ws_size,
                              hipStream_t stream)
{
  static const int NT[6] = {25000, 15000, 4000, 12000, 12000, 15000};
  static const int REL_S[19] = {2,0,2,1,0,1,3,3,1,3,1,3,4,5,0,5,1,0,1};
  static const int REL_D[19] = {0,2,1,2,1,0,3,1,3,1,3,4,3,0,5,1,5,1,0};

  auto xin   = [&](int t, int L) { return (const float*)d_in[L * 13 + 2 * t]; };
  auto mapin = [&](int t, int L) { return (const int*)d_in[L * 13 + 2 * t + 1]; };
  const int* edges0 = (const int*)d_in[12];
  const int* edges1 = (const int*)d_in[25];
  const float* W_in_atac  = (const float*)d_in[26];
  const float* b_in_atac  = (const float*)d_in[27];
  const float* W_in_gene  = (const float*)d_in[28];
  const float* b_in_gene  = (const float*)d_in[29];
  const float* W_in_pname = (const float*)d_in[30];
  const float* b_in_pname = (const float*)d_in[31];
  const float* conv_wl = (const float*)d_in[32];
  const float* conv_bl = (const float*)d_in[33];
  const float* conv_wr = (const float*)d_in[34];
  const float* mlp_w1 = (const float*)d_in[35];
  const float* mlp_b1 = (const float*)d_in[36];
  const float* mlp_w2 = (const float*)d_in[37];
  const float* mlp_b2 = (const float*)d_in[38];
  const float* gd_w1 = (const float*)d_in[39];
  const float* gd_b1 = (const float*)d_in[40];
  const float* gd_w2 = (const float*)d_in[41];
  const float* gd_b2 = (const float*)d_in[42];
  const float* gv_w1 = (const float*)d_in[43];
  const float* gv_b1 = (const float*)d_in[44];
  const float* gv_w2 = (const float*)d_in[45];
  const float* gv_b2 = (const float*)d_in[46];
  float* out = (float*)d_out;

  // ---- workspace carve (floats then ints) ----
  float* p = (float*)d_ws;
  auto take = [&](size_t n) { float* q = p; p += n; return q; };
  float* X0a  = take((size_t)25000 * 128);
  float* X0g  = take((size_t)15000 * 128);
  float* X0p  = take((size_t)12000 * 128);
  float* X1a  = take((size_t)25000 * 128);
  float* X1g  = take((size_t)15000 * 128);
  float* X1t  = take((size_t)4000 * 128);
  float* X1pr = take((size_t)12000 * 128);
  float* X1e  = take((size_t)15000 * 128);
  float* NW[6];
  NW[0] = take((size_t)25000 * 128);
  NW[1] = take((size_t)15000 * 128);
  NW[2] = take((size_t)4000 * 128);
  NW[3] = take((size_t)12000 * 128);
  NW[4] = nullptr;
  NW[5] = take((size_t)15000 * 128);
  float* G1  = take((size_t)15000 * 128);
  float* HID = take((size_t)25000 * 256);
  float* WRS = take((size_t)5 * 16384);
  float* BLS = take((size_t)5 * 128);
  int* ip = (int*)p;
  auto takei = [&](size_t n) { int* q = ip; ip += n; return q; };
  int* CNT  = takei(276000);
  int* RP   = takei(276018);
  int* CUR  = takei(276018);
  int* ESRC = takei((size_t)18 * E_EDGES);

  const float* X0ptr[6] = {X0a, X0g, xin(2,0), xin(3,0), X0p, xin(5,0)};
  float*       X1ptr[6] = {X1a, X1g, X1t, X1pr, nullptr, X1e};

  static const int GD[5]       = {0, 1, 2, 3, 5};
  static const int GNR[5]      = {4, 6, 2, 4, 2};
  static const int GRELS[5][6] = {{0,5,13,18,0,0},{2,4,7,9,15,17},{1,3,0,0,0,0},
                                  {6,8,10,12,0,0},{14,16,0,0,0,0}};

  WsumArgs wa;
  for (int g = 0; g < 5; g++) {
    wa.nrels[g] = GNR[g];
    for (int i = 0; i < 6; i++) wa.relid[g][i] = GRELS[g][i];
  }
  hipLaunchKernelGGL(wrsum_kernel, dim3(320), dim3(256), 0, stream,
                     conv_wr, conv_bl, WRS, BLS, wa);

  auto gemm = [&](const float* A, const float* W, const float* b, float* C,
                  int M, int K, int N, int relu) {
    hipLaunchKernelGGL(gemm_kernel, dim3((M + 63) / 64, N / 128), dim3(256), 0, stream,
                       A, W, b, C, M, K, N, relu);
  };

  gemm(xin(0,0), W_in_atac,  b_in_atac,  X0a, 25000, 257, 128, 0);
  gemm(xin(1,0), W_in_gene,  b_in_gene,  X0g, 15000, 129, 128, 0);
  gemm(xin(4,0), W_in_pname, b_in_pname, X0p, 12000, 129, 128, 0);
  gemm(xin(0,1), W_in_atac,  b_in_atac,  X1a, 25000, 257, 128, 0);
  gemm(xin(1,1), W_in_gene,  b_in_gene,  X1g, 15000, 129, 128, 0);
  hipMemcpyAsync(X1t,  xin(2,1), (size_t)4000  * 128 * 4, hipMemcpyDeviceToDevice, stream);
  hipMemcpyAsync(X1pr, xin(3,1), (size_t)12000 * 128 * 4, hipMemcpyDeviceToDevice, stream);
  hipMemcpyAsync(X1e,  xin(5,1), (size_t)15000 * 128 * 4, hipMemcpyDeviceToDevice, stream);

  // CSR layer 0 (18 live relations)
  static const int L0R[18] = {0,1,2,3,4,5,6,7,8,9,10,12,13,14,15,16,17,18};
  int rpoffByRel[19], slotByRel[19];
  CsrArgs c0; c0.nslots = 18;
  {
    int co = 0, ro = 0;
    for (int s = 0; s < 18; s++) {
      int r = L0R[s];
      c0.relid[s] = r; int nd = NT[REL_D[r]];
      c0.nd[s] = nd; c0.cntoff[s] = co; c0.rpoff[s] = ro;
      rpoffByRel[r] = ro; slotByRel[r] = s;
      co += nd; ro += nd + 1;
    }
    hipMemsetAsync(CNT, 0, (size_t)co * 4, stream);
    hipLaunchKernelGGL(hist_kernel, dim3(391, 18), dim3(256), 0, stream, edges0, CNT, c0);
    hipLaunchKernelGGL(scan_kernel, dim3(18), dim3(256), 0, stream, CNT, RP, c0);
    hipMemcpyAsync(CUR, RP, (size_t)ro * 4, hipMemcpyDeviceToDevice, stream);
    hipLaunchKernelGGL(scatter_kernel, dim3(391, 18), dim3(256), 0, stream, edges0, CUR, ESRC, c0);
  }

  // fused conv layer 0
  for (int g = 0; g < 5; g++) {
    int d = GD[g];
    ConvArgs ca{};
    ca.nrels = GNR[g]; ca.nd = NT[d];
    for (int i = 0; i < GNR[g]; i++) {
      int r = GRELS[g][i];
      ca.xsrc[i]   = X0ptr[REL_S[r]];
      ca.rowptr[i] = RP + rpoffByRel[r];
      ca.epack[i]  = ESRC + (long)slotByRel[r] * E_EDGES;
      ca.wl[i]     = conv_wl + (long)r * 16384;
    }
    ca.xdst = X0ptr[d]; ca.wrsum = WRS + (long)g * 16384; ca.blsum = BLS + g * 128;
    ca.out = NW[d];
    hipLaunchKernelGGL(conv_kernel, dim3((NT[d] + 63) / 64), dim3(256), 0, stream, ca);
  }

  // per-type MLP + cross-layer scatter into X1
  for (int g = 0; g < 5; g++) {
    int d = GD[g];
    gemm(NW[d], mlp_w1 + (long)d * 128 * 256, mlp_b1 + d * 256, HID, NT[d], 128, 256, 1);
    gemm(HID,   mlp_w2 + (long)d * 256 * 128, mlp_b2 + d * 128, NW[d], NT[d], 256, 128, 0);
    hipLaunchKernelGGL(xscatter_kernel, dim3(NT[d]), dim3(128), 0, stream,
                       mapin(d,0), mapin(d,1), NW[d], X1ptr[d], NT[d]);
  }

  // CSR layer 1 (gene-dst relations only)
  static const int L1R[6] = {2, 4, 7, 9, 15, 17};
  int rpoff1[19], slot1[19];
  CsrArgs c1; c1.nslots = 6;
  {
    int co = 0, ro = 0;
    for (int s = 0; s < 6; s++) {
      int r = L1R[s];
      c1.relid[s] = r; c1.nd[s] = 15000; c1.cntoff[s] = co; c1.rpoff[s] = ro;
      rpoff1[r] = ro; slot1[r] = s;
      co += 15000; ro += 15001;
    }
    hipMemsetAsync(CNT, 0, (size_t)co * 4, stream);
    hipLaunchKernelGGL(hist_kernel, dim3(391, 6), dim3(256), 0, stream, edges1, CNT, c1);
    hipLaunchKernelGGL(scan_kernel, dim3(6), dim3(256), 0, stream, CNT, RP, c1);
    hipMemcpyAsync(CUR, RP, (size_t)ro * 4, hipMemcpyDeviceToDevice, stream);
    hipLaunchKernelGGL(scatter_kernel, dim3(391, 6), dim3(256), 0, stream, edges1, CUR, ESRC, c1);
  }

  // fused conv layer 1, gene only
  {
    ConvArgs ca{};
    ca.nrels = 6; ca.nd = 15000;
    for (int i = 0; i < 6; i++) {
      int r = L1R[i];
      ca.xsrc[i]   = X1ptr[REL_S[r]];
      ca.rowptr[i] = RP + rpoff1[r];
      ca.epack[i]  = ESRC + (long)slot1[r] * E_EDGES;
      ca.wl[i]     = conv_wl + (long)r * 16384;
    }
    ca.xdst = X1g; ca.wrsum = WRS + 1 * 16384; ca.blsum = BLS + 1 * 128; ca.out = G1;
    hipLaunchKernelGGL(conv_kernel, dim3((15000 + 63) / 64), dim3(256), 0, stream, ca);
  }

  // gene heads
  gemm(G1, gd_w1, gd_b1, HID, 15000, 128, 256, 1);
  hipLaunchKernelGGL(head_reduce_kernel, dim3(15000), dim3(64), 0, stream,
                     HID, gd_w2, gd_b2, out, 0, 1);
  gemm(G1, gv_w1, gv_b1, HID, 15000, 128, 256, 1);
  hipLaunchKernelGGL(head_reduce_kernel, dim3(15000), dim3(64), 0, stream,
                     HID, gv_w2, gv_b2, out, 1, 0);
}

// Round 3
// 1967.262 us; speedup vs baseline: 2.3366x; 2.3366x over previous
//
#include <hip/hip_runtime.h>
#include <math.h>

#define E_EDGES 100000

typedef unsigned short u16;
typedef unsigned int u32;

__device__ inline float bf2f(u32 u) { union { u32 i; float f; } c; c.i = u << 16; return c.f; }
__device__ inline u16 f2bf(float f) {
  union { u32 i; float f; } c; c.f = f;
  u32 u = c.i;
  return (u16)((u + 0x7FFFu + ((u >> 16) & 1u)) >> 16);
}

// ---------------- structs ----------------
struct CsrArgs { int nslots; int relid[18]; int nd[18]; int cntoff[18]; int rpoff[18]; };

struct AggArgs {
  const u16* xsrc[7];   // per slot src table; slot nrels = xdst table
  const int* rowptr[6];
  const int* esrc[6];
  u16* abuf;
  int nrels, nd, pitch;
};

struct WStackArgs {
  int srcrel[23];  // >=0: copy wl[r]; <0: sum-of-wr slot
  int grp[23];
  int outoff[23];  // element offset into WG
  int nslots;
  int gnr[5];
  int grel[5][6];
};

// ---------------- unified GEMM: C = op(A[M,K] @ W[K,N] + b) ----------------
// ABF: A is bf16 (requires K%32==0). OBF: output bf16. RELU: relu epilogue.
template <int ABF, int OBF, int RELU>
__global__ __launch_bounds__(256) void gemm_t(const void* __restrict__ Av,
                                              const float* __restrict__ W,
                                              const float* __restrict__ bias,
                                              void* __restrict__ Cv,
                                              int M, int K, int N)
{
  __shared__ float sA[64][36];
  const int tid = threadIdx.x;
  const int tx = tid & 31, ty = tid >> 5;
  const int rowbase = blockIdx.x * 64;
  const int colbase = blockIdx.y * 128;
  float acc[8][4];
  #pragma unroll
  for (int i = 0; i < 8; i++)
    #pragma unroll
    for (int j = 0; j < 4; j++) acc[i][j] = 0.f;

  for (int k0 = 0; k0 < K; k0 += 32) {
    if (ABF) {
      // 64 rows x 32 k of bf16: one 16B load (8 bf16) per thread
      const u16* A = (const u16*)Av;
      int r = tid >> 2, ks = (tid & 3) * 8;
      int gr = rowbase + r;
      float v[8];
      if (gr < M) {
        uint4 u = *(const uint4*)(A + (long)gr * K + k0 + ks);
        v[0] = bf2f(u.x & 0xFFFF); v[1] = bf2f(u.x >> 16);
        v[2] = bf2f(u.y & 0xFFFF); v[3] = bf2f(u.y >> 16);
        v[4] = bf2f(u.z & 0xFFFF); v[5] = bf2f(u.z >> 16);
        v[6] = bf2f(u.w & 0xFFFF); v[7] = bf2f(u.w >> 16);
      } else {
        #pragma unroll
        for (int i = 0; i < 8; i++) v[i] = 0.f;
      }
      #pragma unroll
      for (int i = 0; i < 8; i++) sA[r][ks + i] = v[i];
    } else {
      const float* A = (const float*)Av;
      #pragma unroll
      for (int i = 0; i < 8; i++) {
        int flat = tid + i * 256;
        int kk = flat & 31, r = flat >> 5;
        int gr = rowbase + r, gk = k0 + kk;
        sA[r][kk] = (gr < M && gk < K) ? A[(long)gr * K + gk] : 0.f;
      }
    }
    __syncthreads();
    #pragma unroll 8
    for (int kk = 0; kk < 32; kk++) {
      float4 wv = make_float4(0.f, 0.f, 0.f, 0.f);
      if (k0 + kk < K) wv = *(const float4*)&W[(long)(k0 + kk) * N + colbase + tx * 4];
      #pragma unroll
      for (int i = 0; i < 8; i++) {
        float av = sA[ty * 8 + i][kk];
        acc[i][0] += av * wv.x; acc[i][1] += av * wv.y;
        acc[i][2] += av * wv.z; acc[i][3] += av * wv.w;
      }
    }
    __syncthreads();
  }
  float4 bv = make_float4(0.f, 0.f, 0.f, 0.f);
  if (bias) bv = *(const float4*)&bias[colbase + tx * 4];
  #pragma unroll
  for (int i = 0; i < 8; i++) {
    int gr = rowbase + ty * 8 + i;
    if (gr < M) {
      float4 o;
      o.x = acc[i][0] + bv.x; o.y = acc[i][1] + bv.y;
      o.z = acc[i][2] + bv.z; o.w = acc[i][3] + bv.w;
      if (RELU) { o.x = fmaxf(o.x, 0.f); o.y = fmaxf(o.y, 0.f); o.z = fmaxf(o.z, 0.f); o.w = fmaxf(o.w, 0.f); }
      long off = (long)gr * N + colbase + tx * 4;
      if (OBF) {
        ushort4 o4; o4.x = f2bf(o.x); o4.y = f2bf(o.y); o4.z = f2bf(o.z); o4.w = f2bf(o.w);
        *(ushort4*)((u16*)Cv + off) = o4;
      } else {
        *(float4*)((float*)Cv + off) = o;
      }
    }
  }
}

// ---------------- CSR build ----------------
__global__ __launch_bounds__(256) void hist_kernel(const int* __restrict__ edges,
                                                   int* __restrict__ cnt, CsrArgs a)
{
  int slot = blockIdx.y;
  int e = blockIdx.x * 256 + threadIdx.x;
  if (e >= E_EDGES) return;
  int r = a.relid[slot];
  int dst = edges[(r * 2 + 1) * E_EDGES + e];
  atomicAdd(&cnt[a.cntoff[slot] + dst], 1);
}

__global__ __launch_bounds__(256) void scan_kernel(const int* __restrict__ cnt,
                                                   int* __restrict__ rowptr, CsrArgs a)
{
  __shared__ int sbuf[256];
  int slot = blockIdx.x;
  int n = a.nd[slot], cb = a.cntoff[slot], rb = a.rpoff[slot];
  int tid = threadIdx.x;
  int carry = 0;
  for (int c0 = 0; c0 < n; c0 += 256) {
    int i = c0 + tid;
    int v = (i < n) ? cnt[cb + i] : 0;
    sbuf[tid] = v;
    __syncthreads();
    #pragma unroll
    for (int off = 1; off < 256; off <<= 1) {
      int t = (tid >= off) ? sbuf[tid - off] : 0;
      __syncthreads();
      sbuf[tid] += t;
      __syncthreads();
    }
    if (i < n) rowptr[rb + i] = carry + sbuf[tid] - v;
    carry += sbuf[255];
    __syncthreads();
  }
  if (tid == 0) rowptr[rb + n] = carry;
}

__global__ __launch_bounds__(256) void scatter_kernel(const int* __restrict__ edges,
                                                      int* __restrict__ cursor,
                                                      int* __restrict__ esrc, CsrArgs a)
{
  int slot = blockIdx.y;
  int e = blockIdx.x * 256 + threadIdx.x;
  if (e >= E_EDGES) return;
  int r = a.relid[slot];
  int src = edges[r * 2 * E_EDGES + e];
  int dst = edges[(r * 2 + 1) * E_EDGES + e];
  int pos = atomicAdd(&cursor[a.rpoff[slot] + dst], 1);
  esrc[slot * E_EDGES + pos] = src;
}

// ---------------- stacked W + bias sums per dst group ----------------
__global__ __launch_bounds__(256) void wstack_kernel(const float* __restrict__ wl,
                                                     const float* __restrict__ wr,
                                                     const float* __restrict__ bl,
                                                     float* __restrict__ WG,
                                                     float* __restrict__ BLS, WStackArgs a)
{
  int j = blockIdx.y;
  int idx = blockIdx.x * 256 + threadIdx.x;  // 0..16383
  int sr = a.srcrel[j];
  float v;
  if (sr >= 0) {
    v = wl[(long)sr * 16384 + idx];
  } else {
    int g = a.grp[j];
    v = 0.f;
    for (int i = 0; i < a.gnr[g]; i++) v += wr[(long)a.grel[g][i] * 16384 + idx];
    if (idx < 128) {
      float b = 0.f;
      for (int i = 0; i < a.gnr[g]; i++) b += bl[a.grel[g][i] * 128 + idx];
      BLS[g * 128 + idx] = b;
    }
  }
  WG[(long)a.outoff[j] + idx] = v;
}

// ---------------- fp32 -> bf16 convert ----------------
__global__ __launch_bounds__(256) void f2b_kernel(const float* __restrict__ s,
                                                  u16* __restrict__ d, int n4)
{
  int i = blockIdx.x * 256 + threadIdx.x;
  if (i >= n4) return;
  float4 v = ((const float4*)s)[i];
  ushort4 o; o.x = f2bf(v.x); o.y = f2bf(v.y); o.z = f2bf(v.z); o.w = f2bf(v.w);
  ((ushort4*)d)[i] = o;
}

// ---------------- aggregation: one wave per (dst row, relation slot) ----------------
// lane covers 2 features as bf16x2 (4B) -> 256 B coalesced per edge per wave.
__global__ __launch_bounds__(256) void agg_kernel(AggArgs a)
{
  int slot = blockIdx.y;
  int wave = threadIdx.x >> 6, lane = threadIdx.x & 63;
  int row = blockIdx.x * 4 + wave;
  if (row >= a.nd) return;
  u16* dst = a.abuf + (long)row * a.pitch + slot * 128 + lane * 2;
  const u32* x2 = (const u32*)a.xsrc[slot];
  if (slot == a.nrels) {          // x_dst passthrough slot
    *(u32*)dst = x2[(long)row * 64 + lane];
    return;
  }
  const int* rp = a.rowptr[slot];
  int c0 = rp[row], c1 = rp[row + 1];
  const int* es = a.esrc[slot];
  float ax = 0.f, ay = 0.f;
  int e = c0;
  for (; e + 4 <= c1; e += 4) {
    int s0 = es[e], s1 = es[e + 1], s2 = es[e + 2], s3 = es[e + 3];
    u32 v0 = x2[(long)s0 * 64 + lane];
    u32 v1 = x2[(long)s1 * 64 + lane];
    u32 v2 = x2[(long)s2 * 64 + lane];
    u32 v3 = x2[(long)s3 * 64 + lane];
    ax += bf2f(v0 & 0xFFFF) + bf2f(v1 & 0xFFFF) + bf2f(v2 & 0xFFFF) + bf2f(v3 & 0xFFFF);
    ay += bf2f(v0 >> 16) + bf2f(v1 >> 16) + bf2f(v2 >> 16) + bf2f(v3 >> 16);
  }
  for (; e < c1; e++) {
    u32 v = x2[(long)es[e] * 64 + lane];
    ax += bf2f(v & 0xFFFF);
    ay += bf2f(v >> 16);
  }
  int c = c1 - c0;
  float inv = 1.f / (float)(c > 1 ? c : 1);
  ax *= inv; ay *= inv;
  *(u32*)dst = (u32)f2bf(ax) | ((u32)f2bf(ay) << 16);
}

// ---------------- cross-layer scatter (bf16 rows, binary search on sorted ids) --------
__global__ __launch_bounds__(64) void xscatter_b(const int* __restrict__ map0,
                                                 const int* __restrict__ map1,
                                                 const u16* __restrict__ src,
                                                 u16* __restrict__ dst, int n)
{
  __shared__ int spos;
  int j = blockIdx.x;
  if (threadIdx.x == 0) {
    int key = map1[j];
    int lo = 0, hi = n - 1, pos = -1;
    while (lo <= hi) {
      int mid = (lo + hi) >> 1;
      int v = map0[mid];
      if (v == key) { pos = mid; break; }
      if (v < key) lo = mid + 1; else hi = mid - 1;
    }
    spos = pos;
  }
  __syncthreads();
  int p = spos;
  if (p >= 0)
    ((u32*)dst)[(long)j * 64 + threadIdx.x] = ((const u32*)src)[(long)p * 64 + threadIdx.x];
}

// ---------------- head: out[row*2+col] = post(hid[row,:256] . w2 + b2) ----------------
__global__ __launch_bounds__(64) void head_reduce_kernel(const float* __restrict__ hid,
                                                         const float* __restrict__ w2,
                                                         const float* __restrict__ b2,
                                                         float* __restrict__ out,
                                                         int col, int dosig)
{
  int row = blockIdx.x;
  int lane = threadIdx.x;
  const float* h = hid + (long)row * 256;
  float s = h[lane] * w2[lane] + h[lane + 64] * w2[lane + 64]
          + h[lane + 128] * w2[lane + 128] + h[lane + 192] * w2[lane + 192];
  #pragma unroll
  for (int off = 32; off >= 1; off >>= 1) s += __shfl_down(s, off, 64);
  if (lane == 0) {
    float v = s + b2[0];
    if (dosig) v = 1.0f / (1.0f + expf(-v));
    out[row * 2 + col] = v;
  }
}

// ---------------- host orchestration ----------------
extern "C" void kernel_launch(void* const* d_in, const int* in_sizes, int n_in,
                              void* d_out, int out_size, void* d_ws, size_t ws_size,
                              hipStream_t stream)
{
  static const int NT[6] = {25000, 15000, 4000, 12000, 12000, 15000};
  static const int REL_S[19] = {2,0,2,1,0,1,3,3,1,3,1,3,4,5,0,5,1,0,1};
  static const int REL_D[19] = {0,2,1,2,1,0,3,1,3,1,3,4,3,0,5,1,5,1,0};

  auto xin   = [&](int t, int L) { return (const float*)d_in[L * 13 + 2 * t]; };
  auto mapin = [&](int t, int L) { return (const int*)d_in[L * 13 + 2 * t + 1]; };
  const int* edges0 = (const int*)d_in[12];
  const int* edges1 = (const int*)d_in[25];
  const float* W_in_atac  = (const float*)d_in[26];
  const float* b_in_atac  = (const float*)d_in[27];
  const float* W_in_gene  = (const float*)d_in[28];
  const float* b_in_gene  = (const float*)d_in[29];
  const float* W_in_pname = (const float*)d_in[30];
  const float* b_in_pname = (const float*)d_in[31];
  const float* conv_wl = (const float*)d_in[32];
  const float* conv_bl = (const float*)d_in[33];
  const float* conv_wr = (const float*)d_in[34];
  const float* mlp_w1 = (const float*)d_in[35];
  const float* mlp_b1 = (const float*)d_in[36];
  const float* mlp_w2 = (const float*)d_in[37];
  const float* mlp_b2 = (const float*)d_in[38];
  const float* gd_w1 = (const float*)d_in[39];
  const float* gd_b1 = (const float*)d_in[40];
  const float* gd_w2 = (const float*)d_in[41];
  const float* gd_b2 = (const float*)d_in[42];
  const float* gv_w1 = (const float*)d_in[43];
  const float* gv_b1 = (const float*)d_in[44];
  const float* gv_w2 = (const float*)d_in[45];
  const float* gv_b2 = (const float*)d_in[46];
  float* out = (float*)d_out;

  // ---- workspace carve: fp32, then bf16, then int ----
  float* fp = (float*)d_ws;
  auto takef = [&](size_t n) { float* q = fp; fp += n; return q; };
  float* G1   = takef((size_t)15000 * 128);
  float* HIDF = takef((size_t)15000 * 256);
  float* WG   = takef(376832);
  float* BLS  = takef(5 * 128);
  u16* bp = (u16*)fp;
  auto takeb = [&](size_t n) { u16* q = bp; bp += n; return q; };
  u16* XB0[6]; u16* XB1[6];
  XB0[0] = takeb((size_t)25000 * 128);
  XB0[1] = takeb((size_t)15000 * 128);
  XB0[2] = takeb((size_t)4000 * 128);
  XB0[3] = takeb((size_t)12000 * 128);
  XB0[4] = takeb((size_t)12000 * 128);
  XB0[5] = takeb((size_t)15000 * 128);
  XB1[0] = takeb((size_t)25000 * 128);
  XB1[1] = takeb((size_t)15000 * 128);
  XB1[2] = takeb((size_t)4000 * 128);
  XB1[3] = takeb((size_t)12000 * 128);
  XB1[4] = nullptr;                          // pname layer-1 is dead code
  XB1[5] = takeb((size_t)15000 * 128);
  u16* ABUF = takeb((size_t)25000 * 640);    // max group (atac L0); gene 15000*896 fits
  u16* NWB  = takeb((size_t)25000 * 128);
  u16* HIDB = takeb((size_t)25000 * 256);
  u16* MOUT = takeb((size_t)25000 * 128);
  // align to 16B for int section
  uintptr_t ipa = ((uintptr_t)bp + 15) & ~(uintptr_t)15;
  int* ip = (int*)ipa;
  auto takei = [&](size_t n) { int* q = ip; ip += n; return q; };
  int* CNT  = takei(276000);
  int* RP   = takei(276018);
  int* CUR  = takei(276018);
  int* ESRC = takei((size_t)18 * E_EDGES);

  // dst-type groups
  static const int GD[5]       = {0, 1, 2, 3, 5};
  static const int GNR[5]      = {4, 6, 2, 4, 2};
  static const int GRELS[5][6] = {{0,5,13,18,0,0},{2,4,7,9,15,17},{1,3,0,0,0,0},
                                  {6,8,10,12,0,0},{14,16,0,0,0,0}};
  static const int GPITCH[5]   = {640, 896, 384, 640, 384};
  int groupWbase[5];
  {
    int o = 0;
    for (int g = 0; g < 5; g++) { groupWbase[g] = o; o += (GNR[g] + 1) * 16384; }
  }

  // 1) stacked W + bias sums
  {
    WStackArgs wa{};
    int j = 0;
    for (int g = 0; g < 5; g++) {
      wa.gnr[g] = GNR[g];
      for (int i = 0; i < 6; i++) wa.grel[g][i] = GRELS[g][i];
      for (int s = 0; s <= GNR[g]; s++, j++) {
        wa.srcrel[j] = (s < GNR[g]) ? GRELS[g][s] : -1;
        wa.grp[j] = g;
        wa.outoff[j] = groupWbase[g] + s * 16384;
      }
    }
    wa.nslots = j;
    hipLaunchKernelGGL(wstack_kernel, dim3(64, 23), dim3(256), 0, stream,
                       conv_wl, conv_wr, conv_bl, WG, BLS, wa);
  }

  auto gemm_f_b = [&](const float* A, const float* W, const float* b, u16* C,
                      int M, int K, int N, int relu) {
    if (relu)
      hipLaunchKernelGGL(HIP_KERNEL_NAME(gemm_t<0,1,1>), dim3((M+63)/64, N/128), dim3(256), 0, stream, A, W, b, C, M, K, N);
    else
      hipLaunchKernelGGL(HIP_KERNEL_NAME(gemm_t<0,1,0>), dim3((M+63)/64, N/128), dim3(256), 0, stream, A, W, b, C, M, K, N);
  };
  auto gemm_b_b = [&](const u16* A, const float* W, const float* b, u16* C,
                      int M, int K, int N, int relu) {
    if (relu)
      hipLaunchKernelGGL(HIP_KERNEL_NAME(gemm_t<1,1,1>), dim3((M+63)/64, N/128), dim3(256), 0, stream, A, W, b, C, M, K, N);
    else
      hipLaunchKernelGGL(HIP_KERNEL_NAME(gemm_t<1,1,0>), dim3((M+63)/64, N/128), dim3(256), 0, stream, A, W, b, C, M, K, N);
  };

  // 2) input linears -> bf16 tables; raw tables converted
  gemm_f_b(xin(0,0), W_in_atac,  b_in_atac,  XB0[0], 25000, 257, 128, 0);
  gemm_f_b(xin(1,0), W_in_gene,  b_in_gene,  XB0[1], 15000, 129, 128, 0);
  gemm_f_b(xin(4,0), W_in_pname, b_in_pname, XB0[4], 12000, 129, 128, 0);
  gemm_f_b(xin(0,1), W_in_atac,  b_in_atac,  XB1[0], 25000, 257, 128, 0);
  gemm_f_b(xin(1,1), W_in_gene,  b_in_gene,  XB1[1], 15000, 129, 128, 0);
  auto conv_tbl = [&](const float* s, u16* d, int nrows) {
    int n4 = nrows * 32;
    hipLaunchKernelGGL(f2b_kernel, dim3((n4 + 255) / 256), dim3(256), 0, stream, s, d, n4);
  };
  conv_tbl(xin(2,0), XB0[2], 4000);
  conv_tbl(xin(3,0), XB0[3], 12000);
  conv_tbl(xin(5,0), XB0[5], 15000);
  conv_tbl(xin(2,1), XB1[2], 4000);
  conv_tbl(xin(3,1), XB1[3], 12000);
  conv_tbl(xin(5,1), XB1[5], 15000);

  // 3) CSR layer 0 (18 live relations; rel 11 = (3,4) is dead)
  static const int L0R[18] = {0,1,2,3,4,5,6,7,8,9,10,12,13,14,15,16,17,18};
  int rpoffByRel[19], slotByRel[19];
  CsrArgs c0; c0.nslots = 18;
  {
    int co = 0, ro = 0;
    for (int s = 0; s < 18; s++) {
      int r = L0R[s];
      c0.relid[s] = r; int nd = NT[REL_D[r]];
      c0.nd[s] = nd; c0.cntoff[s] = co; c0.rpoff[s] = ro;
      rpoffByRel[r] = ro; slotByRel[r] = s;
      co += nd; ro += nd + 1;
    }
    hipMemsetAsync(CNT, 0, (size_t)co * 4, stream);
    hipLaunchKernelGGL(hist_kernel, dim3(391, 18), dim3(256), 0, stream, edges0, CNT, c0);
    hipLaunchKernelGGL(scan_kernel, dim3(18), dim3(256), 0, stream, CNT, RP, c0);
    hipMemcpyAsync(CUR, RP, (size_t)ro * 4, hipMemcpyDeviceToDevice, stream);
    hipLaunchKernelGGL(scatter_kernel, dim3(391, 18), dim3(256), 0, stream, edges0, CUR, ESRC, c0);
  }

  // 4) per dst group: aggregate -> group GEMM -> MLP -> scatter into layer-1 tables
  for (int g = 0; g < 5; g++) {
    int d = GD[g];
    AggArgs aa{};
    aa.nrels = GNR[g]; aa.nd = NT[d]; aa.pitch = GPITCH[g]; aa.abuf = ABUF;
    for (int i = 0; i < GNR[g]; i++) {
      int r = GRELS[g][i];
      aa.xsrc[i]   = XB0[REL_S[r]];
      aa.rowptr[i] = RP + rpoffByRel[r];
      aa.esrc[i]   = ESRC + (long)slotByRel[r] * E_EDGES;
    }
    aa.xsrc[GNR[g]] = XB0[d];
    hipLaunchKernelGGL(agg_kernel, dim3((NT[d] + 3) / 4, GNR[g] + 1), dim3(256), 0, stream, aa);
    // conv GEMM: [Nd x pitch](bf16) @ WG_g + BLS_g -> NWB (bf16)
    gemm_b_b(ABUF, WG + groupWbase[g], BLS + g * 128, NWB, NT[d], GPITCH[g], 128, 0);
    // MLP
    gemm_b_b(NWB,  mlp_w1 + (long)d * 128 * 256, mlp_b1 + d * 256, HIDB, NT[d], 128, 256, 1);
    gemm_b_b(HIDB, mlp_w2 + (long)d * 256 * 128, mlp_b2 + d * 128, MOUT, NT[d], 256, 128, 0);
    hipLaunchKernelGGL(xscatter_b, dim3(NT[d]), dim3(64), 0, stream,
                       mapin(d,0), mapin(d,1), MOUT, XB1[d], NT[d]);
  }

  // 5) CSR layer 1 (gene-dst relations only)
  static const int L1R[6] = {2, 4, 7, 9, 15, 17};
  int rpoff1[19];
  CsrArgs c1; c1.nslots = 6;
  {
    int co = 0, ro = 0;
    for (int s = 0; s < 6; s++) {
      int r = L1R[s];
      c1.relid[s] = r; c1.nd[s] = 15000; c1.cntoff[s] = co; c1.rpoff[s] = ro;
      rpoff1[r] = ro;
      co += 15000; ro += 15001;
    }
    hipMemsetAsync(CNT, 0, (size_t)co * 4, stream);
    hipLaunchKernelGGL(hist_kernel, dim3(391, 6), dim3(256), 0, stream, edges1, CNT, c1);
    hipLaunchKernelGGL(scan_kernel, dim3(6), dim3(256), 0, stream, CNT, RP, c1);
    hipMemcpyAsync(CUR, RP, (size_t)ro * 4, hipMemcpyDeviceToDevice, stream);
    hipLaunchKernelGGL(scatter_kernel, dim3(391, 6), dim3(256), 0, stream, edges1, CUR, ESRC, c1);
  }

  // 6) layer-1 gene conv: aggregate + GEMM -> G1 (fp32)
  {
    AggArgs aa{};
    aa.nrels = 6; aa.nd = 15000; aa.pitch = 896; aa.abuf = ABUF;
    for (int i = 0; i < 6; i++) {
      int r = L1R[i];
      aa.xsrc[i]   = XB1[REL_S[r]];
      aa.rowptr[i] = RP + rpoff1[r];
      aa.esrc[i]   = ESRC + (long)i * E_EDGES;
    }
    aa.xsrc[6] = XB1[1];
    hipLaunchKernelGGL(agg_kernel, dim3((15000 + 3) / 4, 7), dim3(256), 0, stream, aa);
    hipLaunchKernelGGL(HIP_KERNEL_NAME(gemm_t<1,0,0>), dim3((15000+63)/64, 1), dim3(256), 0, stream,
                       ABUF, WG + groupWbase[1], BLS + 1 * 128, G1, 15000, 896, 128);
  }

  // 7) gene heads (fp32)
  hipLaunchKernelGGL(HIP_KERNEL_NAME(gemm_t<0,0,1>), dim3((15000+63)/64, 2), dim3(256), 0, stream,
                     G1, gd_w1, gd_b1, HIDF, 15000, 128, 256);
  hipLaunchKernelGGL(head_reduce_kernel, dim3(15000), dim3(64), 0, stream,
                     HIDF, gd_w2, gd_b2, out, 0, 1);
  hipLaunchKernelGGL(HIP_KERNEL_NAME(gemm_t<0,0,1>), dim3((15000+63)/64, 2), dim3(256), 0, stream,
                     G1, gv_w1, gv_b1, HIDF, 15000, 128, 256);
  hipLaunchKernelGGL(head_reduce_kernel, dim3(15000), dim3(64), 0, stream,
                     HIDF, gv_w2, gv_b2, out, 1, 0);
}

// Round 6
// 1243.441 us; speedup vs baseline: 3.6968x; 1.5821x over previous
//
#include <hip/hip_runtime.h>
#include <math.h>

#define E_EDGES 100000

typedef unsigned short u16;
typedef unsigned int u32;

using bfrag = __attribute__((ext_vector_type(8))) short;
using ffrag = __attribute__((ext_vector_type(4))) float;

__device__ inline float bf2f(u32 u) { union { u32 i; float f; } c; c.i = u << 16; return c.f; }
__device__ inline u16 f2bf(float f) {
  union { u32 i; float f; } c; c.f = f;
  u32 u = c.i;
  return (u16)((u + 0x7FFFu + ((u >> 16) & 1u)) >> 16);
}

// ---------------- structs ----------------
struct CsrArgs { int nslots; int relid[18]; int nd[18]; int cntoff[18]; int rpoff[18]; };

struct AggArgs {
  const u16* xsrc[7];   // per slot src table; slot nrels = xdst table
  const int* rowptr[6];
  const int* esrc[6];
  u16* abuf;
  int nrels, nd, pitch;
};

struct WTStackArgs {
  int srcrel[23];   // >=0: wl[r]; <0: sum-of-wr slot
  int grp[23];
  long outoff[23];  // element offset of group base in WTG
  int koff[23];     // slot's K offset within group (s*128)
  int pitch[23];    // group K pitch
  int gnr[5];
  int grel[5][6];
};

struct WTArgs { const float* W[13]; u16* out[13]; int K[13]; int N[13]; int Kpad[13]; };

// ---------------- MFMA GEMM, m92-style: A and W^T both staged in LDS ----------------
// WT is W transposed: WT[n][k], row-major, rows length Kpad, bf16, zero-padded k>=K.
// Block 256 = 4 waves; tile 64(M) x 128(N); wave w covers rows w*16..w*16+15.
// A-fragment and B-fragment use the IDENTICAL lds read pattern (band*16+(lane&15), k=quad*8+j).
template <int AF32, int OF32, int RELU>
__global__ __launch_bounds__(256) void tgemm(const void* __restrict__ Av,
                                             const u16* __restrict__ WT,
                                             const float* __restrict__ bias,
                                             void* __restrict__ Cv,
                                             int M, int K, int Kpad, int N)
{
  __shared__ u16 sA[64 * 40];
  __shared__ u16 sB[128 * 40];
  const int tid = threadIdx.x;
  const int w = tid >> 6, lane = tid & 63;
  const int quad = lane >> 4, m = lane & 15;
  const int rowbase = blockIdx.x * 64;
  const int colbase = blockIdx.y * 128;
  const int sr = tid >> 2, sc = tid & 3;   // A staging: row 0..63, 8-elem chunk 0..3
  const int br = tid >> 1, bh = tid & 1;   // B staging: row 0..127, 16-elem half 0..1
  ffrag acc[8];
  #pragma unroll
  for (int i = 0; i < 8; i++) { acc[i][0] = 0.f; acc[i][1] = 0.f; acc[i][2] = 0.f; acc[i][3] = 0.f; }

  for (int kt = 0; kt < Kpad / 32; kt++) {
    // ---- A tile load ----
    int gr = rowbase + sr, gk = kt * 32 + sc * 8;
    uint4 st = make_uint4(0, 0, 0, 0);
    if (AF32) {
      const float* A = (const float*)Av;
      if (gr < M) {
        const float* row = A + (long)gr * K + gk;
        float v[8];
        #pragma unroll
        for (int i = 0; i < 8; i++) v[i] = (gk + i < K) ? row[i] : 0.f;
        st.x = (u32)f2bf(v[0]) | ((u32)f2bf(v[1]) << 16);
        st.y = (u32)f2bf(v[2]) | ((u32)f2bf(v[3]) << 16);
        st.z = (u32)f2bf(v[4]) | ((u32)f2bf(v[5]) << 16);
        st.w = (u32)f2bf(v[6]) | ((u32)f2bf(v[7]) << 16);
      }
    } else {
      const u16* A = (const u16*)Av;
      if (gr < M) st = *(const uint4*)(A + (long)gr * K + gk);
    }
    // ---- W^T tile load (rows colbase..colbase+127, fully sized buffer, no guard) ----
    const u16* wrow = WT + (long)(colbase + br) * Kpad + kt * 32 + bh * 16;
    uint4 b0 = *(const uint4*)wrow;
    uint4 b1 = *(const uint4*)(wrow + 8);

    if (kt) __syncthreads();
    *(uint4*)&sA[sr * 40 + sc * 8] = st;
    *(uint4*)&sB[br * 40 + bh * 16] = b0;
    *(uint4*)&sB[br * 40 + bh * 16 + 8] = b1;
    __syncthreads();

    bfrag a = *(const bfrag*)&sA[(w * 16 + m) * 40 + quad * 8];
    #pragma unroll
    for (int ct = 0; ct < 8; ct++) {
      bfrag b = *(const bfrag*)&sB[(ct * 16 + m) * 40 + quad * 8];
      acc[ct] = __builtin_amdgcn_mfma_f32_16x16x32_bf16(a, b, acc[ct], 0, 0, 0);
    }
  }

  // C/D layout: col = lane&15, row = quad*4 + reg  [m89/m91]
  #pragma unroll
  for (int ct = 0; ct < 8; ct++) {
    int col = colbase + ct * 16 + m;
    float bv = bias ? bias[col] : 0.f;
    #pragma unroll
    for (int r = 0; r < 4; r++) {
      int row = rowbase + w * 16 + quad * 4 + r;
      if (row < M) {
        float v = acc[ct][r] + bv;
        if (RELU) v = fmaxf(v, 0.f);
        long off = (long)row * N + col;
        if (OF32) ((float*)Cv)[off] = v;
        else ((u16*)Cv)[off] = f2bf(v);
      }
    }
  }
}

// ---------------- proven fp32 vector GEMM (R3), relu, fp32 out — heads only ----------
__global__ __launch_bounds__(256) void hgemm_kernel(const float* __restrict__ A,
                                                    const float* __restrict__ W,
                                                    const float* __restrict__ bias,
                                                    float* __restrict__ C,
                                                    int M, int K, int N)
{
  __shared__ float sA[64][36];
  const int tid = threadIdx.x;
  const int tx = tid & 31, ty = tid >> 5;
  const int rowbase = blockIdx.x * 64;
  const int colbase = blockIdx.y * 128;
  float acc[8][4];
  #pragma unroll
  for (int i = 0; i < 8; i++)
    #pragma unroll
    for (int j = 0; j < 4; j++) acc[i][j] = 0.f;

  for (int k0 = 0; k0 < K; k0 += 32) {
    #pragma unroll
    for (int i = 0; i < 8; i++) {
      int flat = tid + i * 256;
      int kk = flat & 31, r = flat >> 5;
      int gr = rowbase + r, gk = k0 + kk;
      sA[r][kk] = (gr < M && gk < K) ? A[(long)gr * K + gk] : 0.f;
    }
    __syncthreads();
    #pragma unroll 8
    for (int kk = 0; kk < 32; kk++) {
      float4 wv = make_float4(0.f, 0.f, 0.f, 0.f);
      if (k0 + kk < K) wv = *(const float4*)&W[(long)(k0 + kk) * N + colbase + tx * 4];
      #pragma unroll
      for (int i = 0; i < 8; i++) {
        float av = sA[ty * 8 + i][kk];
        acc[i][0] += av * wv.x; acc[i][1] += av * wv.y;
        acc[i][2] += av * wv.z; acc[i][3] += av * wv.w;
      }
    }
    __syncthreads();
  }
  float4 bv = *(const float4*)&bias[colbase + tx * 4];
  #pragma unroll
  for (int i = 0; i < 8; i++) {
    int gr = rowbase + ty * 8 + i;
    if (gr < M) {
      float4 o;
      o.x = fmaxf(acc[i][0] + bv.x, 0.f); o.y = fmaxf(acc[i][1] + bv.y, 0.f);
      o.z = fmaxf(acc[i][2] + bv.z, 0.f); o.w = fmaxf(acc[i][3] + bv.w, 0.f);
      *(float4*)&C[(long)gr * N + colbase + tx * 4] = o;
    }
  }
}

// ---------------- CSR build ----------------
__global__ __launch_bounds__(256) void hist_kernel(const int* __restrict__ edges,
                                                   int* __restrict__ cnt, CsrArgs a)
{
  int slot = blockIdx.y;
  int e = blockIdx.x * 256 + threadIdx.x;
  if (e >= E_EDGES) return;
  int r = a.relid[slot];
  int dst = edges[(r * 2 + 1) * E_EDGES + e];
  atomicAdd(&cnt[a.cntoff[slot] + dst], 1);
}

__global__ __launch_bounds__(256) void scan_kernel(const int* __restrict__ cnt,
                                                   int* __restrict__ rowptr, CsrArgs a)
{
  __shared__ int sbuf[256];
  int slot = blockIdx.x;
  int n = a.nd[slot], cb = a.cntoff[slot], rb = a.rpoff[slot];
  int tid = threadIdx.x;
  int carry = 0;
  for (int c0 = 0; c0 < n; c0 += 256) {
    int i = c0 + tid;
    int v = (i < n) ? cnt[cb + i] : 0;
    sbuf[tid] = v;
    __syncthreads();
    #pragma unroll
    for (int off = 1; off < 256; off <<= 1) {
      int t = (tid >= off) ? sbuf[tid - off] : 0;
      __syncthreads();
      sbuf[tid] += t;
      __syncthreads();
    }
    if (i < n) rowptr[rb + i] = carry + sbuf[tid] - v;
    carry += sbuf[255];
    __syncthreads();
  }
  if (tid == 0) rowptr[rb + n] = carry;
}

__global__ __launch_bounds__(256) void scatter_kernel(const int* __restrict__ edges,
                                                      int* __restrict__ cursor,
                                                      int* __restrict__ esrc, CsrArgs a)
{
  int slot = blockIdx.y;
  int e = blockIdx.x * 256 + threadIdx.x;
  if (e >= E_EDGES) return;
  int r = a.relid[slot];
  int src = edges[r * 2 * E_EDGES + e];
  int dst = edges[(r * 2 + 1) * E_EDGES + e];
  int pos = atomicAdd(&cursor[a.rpoff[slot] + dst], 1);
  esrc[slot * E_EDGES + pos] = src;
}

// ---------------- stacked conv W^T (bf16) + bias sums ----------------
// WT_g[n][kglobal]: slot s of group g occupies kglobal in [s*128,(s+1)*128)
__global__ __launch_bounds__(256) void wtstack_kernel(const float* __restrict__ wl,
                                                      const float* __restrict__ wr,
                                                      const float* __restrict__ bl,
                                                      u16* __restrict__ WTG,
                                                      float* __restrict__ BLS, WTStackArgs a)
{
  int slot = blockIdx.y;
  int t = blockIdx.x * 256 + threadIdx.x;   // 0..16383
  int krel = t & 127, n = t >> 7;
  int sr = a.srcrel[slot];
  float v;
  if (sr >= 0) {
    v = wl[(long)sr * 16384 + krel * 128 + n];
  } else {
    int g = a.grp[slot];
    v = 0.f;
    for (int i = 0; i < a.gnr[g]; i++) v += wr[(long)a.grel[g][i] * 16384 + krel * 128 + n];
    if (t < 128) {
      float b = 0.f;
      for (int i = 0; i < a.gnr[g]; i++) b += bl[a.grel[g][i] * 128 + t];
      BLS[g * 128 + t] = b;
    }
  }
  WTG[a.outoff[slot] + (long)n * a.pitch[slot] + a.koff[slot] + krel] = f2bf(v);
}

// ---------------- generic W^T (batched): out[n*Kpad + k] = W[k][n] ----------------
__global__ __launch_bounds__(256) void wt_kernel(WTArgs a)
{
  int s = blockIdx.y;
  int idx = blockIdx.x * 256 + threadIdx.x;
  int K = a.K[s], N = a.N[s], Kpad = a.Kpad[s];
  if (idx >= N * Kpad) return;
  int n = idx / Kpad, k = idx - n * Kpad;
  a.out[s][idx] = (k < K) ? f2bf(a.W[s][(long)k * N + n]) : (u16)0;
}

// ---------------- fp32 -> bf16 convert ----------------
__global__ __launch_bounds__(256) void f2b_kernel(const float* __restrict__ s,
                                                  u16* __restrict__ d, int n4)
{
  int i = blockIdx.x * 256 + threadIdx.x;
  if (i >= n4) return;
  float4 v = ((const float4*)s)[i];
  ushort4 o; o.x = f2bf(v.x); o.y = f2bf(v.y); o.z = f2bf(v.z); o.w = f2bf(v.w);
  ((ushort4*)d)[i] = o;
}

// ---------------- aggregation: one wave per (dst row, relation slot) ----------------
__global__ __launch_bounds__(256) void agg_kernel(AggArgs a)
{
  int slot = blockIdx.y;
  int wave = threadIdx.x >> 6, lane = threadIdx.x & 63;
  int row = blockIdx.x * 4 + wave;
  if (row >= a.nd) return;
  u16* dst = a.abuf + (long)row * a.pitch + slot * 128 + lane * 2;
  const u32* x2 = (const u32*)a.xsrc[slot];
  if (slot == a.nrels) {          // x_dst passthrough slot
    *(u32*)dst = x2[(long)row * 64 + lane];
    return;
  }
  const int* rp = a.rowptr[slot];
  int c0 = rp[row], c1 = rp[row + 1];
  const int* es = a.esrc[slot];
  float ax = 0.f, ay = 0.f;
  int e = c0;
  for (; e + 4 <= c1; e += 4) {
    int s0 = es[e], s1 = es[e + 1], s2 = es[e + 2], s3 = es[e + 3];
    u32 v0 = x2[(long)s0 * 64 + lane];
    u32 v1 = x2[(long)s1 * 64 + lane];
    u32 v2 = x2[(long)s2 * 64 + lane];
    u32 v3 = x2[(long)s3 * 64 + lane];
    ax += bf2f(v0 & 0xFFFF) + bf2f(v1 & 0xFFFF) + bf2f(v2 & 0xFFFF) + bf2f(v3 & 0xFFFF);
    ay += bf2f(v0 >> 16) + bf2f(v1 >> 16) + bf2f(v2 >> 16) + bf2f(v3 >> 16);
  }
  for (; e < c1; e++) {
    u32 v = x2[(long)es[e] * 64 + lane];
    ax += bf2f(v & 0xFFFF);
    ay += bf2f(v >> 16);
  }
  int c = c1 - c0;
  float inv = 1.f / (float)(c > 1 ? c : 1);
  ax *= inv; ay *= inv;
  *(u32*)dst = (u32)f2bf(ax) | ((u32)f2bf(ay) << 16);
}

// ---------------- cross-layer scatter (bf16 rows, binary search on sorted ids) --------
__global__ __launch_bounds__(64) void xscatter_b(const int* __restrict__ map0,
                                                 const int* __restrict__ map1,
                                                 const u16* __restrict__ src,
                                                 u16* __restrict__ dst, int n)
{
  __shared__ int spos;
  int j = blockIdx.x;
  if (threadIdx.x == 0) {
    int key = map1[j];
    int lo = 0, hi = n - 1, pos = -1;
    while (lo <= hi) {
      int mid = (lo + hi) >> 1;
      int v = map0[mid];
      if (v == key) { pos = mid; break; }
      if (v < key) lo = mid + 1; else hi = mid - 1;
    }
    spos = pos;
  }
  __syncthreads();
  int p = spos;
  if (p >= 0)
    ((u32*)dst)[(long)j * 64 + threadIdx.x] = ((const u32*)src)[(long)p * 64 + threadIdx.x];
}

// ---------------- head: out[row*2+col] = post(hid[row,:256] . w2 + b2) ----------------
__global__ __launch_bounds__(64) void head_reduce_kernel(const float* __restrict__ hid,
                                                         const float* __restrict__ w2,
                                                         const float* __restrict__ b2,
                                                         float* __restrict__ out,
                                                         int col, int dosig)
{
  int row = blockIdx.x;
  int lane = threadIdx.x;
  const float* h = hid + (long)row * 256;
  float s = h[lane] * w2[lane] + h[lane + 64] * w2[lane + 64]
          + h[lane + 128] * w2[lane + 128] + h[lane + 192] * w2[lane + 192];
  #pragma unroll
  for (int off = 32; off >= 1; off >>= 1) s += __shfl_down(s, off, 64);
  if (lane == 0) {
    float v = s + b2[0];
    if (dosig) v = 1.0f / (1.0f + expf(-v));
    out[row * 2 + col] = v;
  }
}

// ---------------- host orchestration ----------------
extern "C" void kernel_launch(void* const* d_in, const int* in_sizes, int n_in,
                              void* d_out, int out_size, void* d_ws, size_t ws_size,
                              hipStream_t stream)
{
  static const int NT[6] = {25000, 15000, 4000, 12000, 12000, 15000};
  static const int REL_S[19] = {2,0,2,1,0,1,3,3,1,3,1,3,4,5,0,5,1,0,1};
  static const int REL_D[19] = {0,2,1,2,1,0,3,1,3,1,3,4,3,0,5,1,5,1,0};

  auto xin   = [&](int t, int L) { return (const float*)d_in[L * 13 + 2 * t]; };
  auto mapin = [&](int t, int L) { return (const int*)d_in[L * 13 + 2 * t + 1]; };
  const int* edges0 = (const int*)d_in[12];
  const int* edges1 = (const int*)d_in[25];
  const float* W_in_atac  = (const float*)d_in[26];
  const float* b_in_atac  = (const float*)d_in[27];
  const float* W_in_gene  = (const float*)d_in[28];
  const float* b_in_gene  = (const float*)d_in[29];
  const float* W_in_pname = (const float*)d_in[30];
  const float* b_in_pname = (const float*)d_in[31];
  const float* conv_wl = (const float*)d_in[32];
  const float* conv_bl = (const float*)d_in[33];
  const float* conv_wr = (const float*)d_in[34];
  const float* mlp_w1 = (const float*)d_in[35];
  const float* mlp_b1 = (const float*)d_in[36];
  const float* mlp_w2 = (const float*)d_in[37];
  const float* mlp_b2 = (const float*)d_in[38];
  const float* gd_w1 = (const float*)d_in[39];
  const float* gd_b1 = (const float*)d_in[40];
  const float* gd_w2 = (const float*)d_in[41];
  const float* gd_b2 = (const float*)d_in[42];
  const float* gv_w1 = (const float*)d_in[43];
  const float* gv_b1 = (const float*)d_in[44];
  const float* gv_w2 = (const float*)d_in[45];
  const float* gv_b2 = (const float*)d_in[46];
  float* out = (float*)d_out;

  // ---- workspace carve (~132 MB), NO aliasing: fp32, bf16, int sections ----
  float* fp = (float*)d_ws;
  auto takef = [&](size_t n) { float* q = fp; fp += n; return q; };
  float* BLS  = takef(5 * 128);
  float* G1   = takef((size_t)15000 * 128);
  float* HIDF = takef((size_t)15000 * 256);
  u16* bp = (u16*)fp;
  auto takeb = [&](size_t n) { u16* q = bp; bp += n; return q; };
  u16* XB0[6]; u16* XB1[6];
  XB0[0] = takeb((size_t)25000 * 128);
  XB0[1] = takeb((size_t)15000 * 128);
  XB0[2] = takeb((size_t)4000 * 128);
  XB0[3] = takeb((size_t)12000 * 128);
  XB0[4] = takeb((size_t)12000 * 128);
  XB0[5] = takeb((size_t)15000 * 128);
  XB1[0] = takeb((size_t)25000 * 128);
  XB1[1] = takeb((size_t)15000 * 128);
  XB1[2] = takeb((size_t)4000 * 128);
  XB1[3] = takeb((size_t)12000 * 128);
  XB1[4] = nullptr;                          // pname layer-1 is dead code
  XB1[5] = takeb((size_t)15000 * 128);
  u16* ABUF = takeb((size_t)16000000);       // = 25000*640; >= 15000*896
  u16* NWB  = takeb((size_t)25000 * 128);
  u16* HIDB = takeb((size_t)25000 * 256);
  u16* MOUT = takeb((size_t)25000 * 128);
  // transposed weights (bf16): WT[n][k], row length = Kpad
  u16* WTG  = takeb(376832);                 // stacked conv: sum_g 128*pitch_g
  u16* WTIA = takeb(128 * 288);
  u16* WTIG = takeb(128 * 160);
  u16* WTIP = takeb(128 * 160);
  u16* WTM1 = takeb((size_t)5 * 32768);      // 256 rows x Kpad=128
  u16* WTM2 = takeb((size_t)5 * 32768);      // 128 rows x Kpad=256
  uintptr_t ipa = ((uintptr_t)bp + 15) & ~(uintptr_t)15;
  int* ip = (int*)ipa;
  auto takei = [&](size_t n) { int* q = ip; ip += n; return q; };
  int* CNT  = takei(276000);
  int* RP   = takei(276018);
  int* CUR  = takei(276018);
  int* ESRC = takei((size_t)18 * E_EDGES);

  // dst-type groups
  static const int GD[5]       = {0, 1, 2, 3, 5};
  static const int GNR[5]      = {4, 6, 2, 4, 2};
  static const int GRELS[5][6] = {{0,5,13,18,0,0},{2,4,7,9,15,17},{1,3,0,0,0,0},
                                  {6,8,10,12,0,0},{14,16,0,0,0,0}};
  static const int GPITCH[5]   = {640, 896, 384, 640, 384};
  long gbaseT[5];
  {
    long o = 0;
    for (int g = 0; g < 5; g++) { gbaseT[g] = o; o += (long)128 * GPITCH[g]; }
  }

  // 1) build transposed weights
  {
    WTStackArgs wa{};
    int j = 0;
    for (int g = 0; g < 5; g++) {
      wa.gnr[g] = GNR[g];
      for (int i = 0; i < 6; i++) wa.grel[g][i] = GRELS[g][i];
      for (int s = 0; s <= GNR[g]; s++, j++) {
        wa.srcrel[j] = (s < GNR[g]) ? GRELS[g][s] : -1;
        wa.grp[j] = g;
        wa.outoff[j] = gbaseT[g];
        wa.koff[j] = s * 128;
        wa.pitch[j] = GPITCH[g];
      }
    }
    hipLaunchKernelGGL(wtstack_kernel, dim3(64, 23), dim3(256), 0, stream,
                       conv_wl, conv_wr, conv_bl, WTG, BLS, wa);
  }
  {
    WTArgs pa{};
    int s = 0;
    auto add = [&](const float* W, u16* o, int K, int N, int Kpad) {
      pa.W[s] = W; pa.out[s] = o; pa.K[s] = K; pa.N[s] = N; pa.Kpad[s] = Kpad; s++;
    };
    add(W_in_atac,  WTIA, 257, 128, 288);
    add(W_in_gene,  WTIG, 129, 128, 160);
    add(W_in_pname, WTIP, 129, 128, 160);
    for (int g = 0; g < 5; g++) {
      int d = GD[g];
      add(mlp_w1 + (long)d * 128 * 256, WTM1 + (long)g * 32768, 128, 256, 128);
      add(mlp_w2 + (long)d * 256 * 128, WTM2 + (long)g * 32768, 256, 128, 256);
    }
    hipLaunchKernelGGL(wt_kernel, dim3(144, 13), dim3(256), 0, stream, pa);
  }

  auto mg = [&](int af32, int of32, int relu, const void* A, const u16* WT,
                const float* b, void* C, int M, int K, int Kpad, int N) {
    dim3 grid((M + 63) / 64, N / 128);
    if (af32) {
      hipLaunchKernelGGL(HIP_KERNEL_NAME(tgemm<1,0,0>), grid, dim3(256), 0, stream, A, WT, b, C, M, K, Kpad, N);
    } else {
      if (of32)      hipLaunchKernelGGL(HIP_KERNEL_NAME(tgemm<0,1,0>), grid, dim3(256), 0, stream, A, WT, b, C, M, K, Kpad, N);
      else if (relu) hipLaunchKernelGGL(HIP_KERNEL_NAME(tgemm<0,0,1>), grid, dim3(256), 0, stream, A, WT, b, C, M, K, Kpad, N);
      else           hipLaunchKernelGGL(HIP_KERNEL_NAME(tgemm<0,0,0>), grid, dim3(256), 0, stream, A, WT, b, C, M, K, Kpad, N);
    }
  };

  // 2) input linears -> bf16 tables; raw tables converted
  mg(1,0,0, xin(0,0), WTIA, b_in_atac,  XB0[0], 25000, 257, 288, 128);
  mg(1,0,0, xin(1,0), WTIG, b_in_gene,  XB0[1], 15000, 129, 160, 128);
  mg(1,0,0, xin(4,0), WTIP, b_in_pname, XB0[4], 12000, 129, 160, 128);
  mg(1,0,0, xin(0,1), WTIA, b_in_atac,  XB1[0], 25000, 257, 288, 128);
  mg(1,0,0, xin(1,1), WTIG, b_in_gene,  XB1[1], 15000, 129, 160, 128);
  auto conv_tbl = [&](const float* s, u16* d, int nrows) {
    int n4 = nrows * 32;
    hipLaunchKernelGGL(f2b_kernel, dim3((n4 + 255) / 256), dim3(256), 0, stream, s, d, n4);
  };
  conv_tbl(xin(2,0), XB0[2], 4000);
  conv_tbl(xin(3,0), XB0[3], 12000);
  conv_tbl(xin(5,0), XB0[5], 15000);
  conv_tbl(xin(2,1), XB1[2], 4000);
  conv_tbl(xin(3,1), XB1[3], 12000);
  conv_tbl(xin(5,1), XB1[5], 15000);

  // 3) CSR layer 0 (18 live relations; rel 11 = (3,4) is dead)
  static const int L0R[18] = {0,1,2,3,4,5,6,7,8,9,10,12,13,14,15,16,17,18};
  int rpoffByRel[19], slotByRel[19];
  CsrArgs c0; c0.nslots = 18;
  {
    int co = 0, ro = 0;
    for (int s = 0; s < 18; s++) {
      int r = L0R[s];
      c0.relid[s] = r; int nd = NT[REL_D[r]];
      c0.nd[s] = nd; c0.cntoff[s] = co; c0.rpoff[s] = ro;
      rpoffByRel[r] = ro; slotByRel[r] = s;
      co += nd; ro += nd + 1;
    }
    hipMemsetAsync(CNT, 0, (size_t)co * 4, stream);
    hipLaunchKernelGGL(hist_kernel, dim3(391, 18), dim3(256), 0, stream, edges0, CNT, c0);
    hipLaunchKernelGGL(scan_kernel, dim3(18), dim3(256), 0, stream, CNT, RP, c0);
    hipMemcpyAsync(CUR, RP, (size_t)ro * 4, hipMemcpyDeviceToDevice, stream);
    hipLaunchKernelGGL(scatter_kernel, dim3(391, 18), dim3(256), 0, stream, edges0, CUR, ESRC, c0);
  }

  // 4) per dst group: aggregate -> conv GEMM -> MLP -> scatter into layer-1 tables
  for (int g = 0; g < 5; g++) {
    int d = GD[g];
    AggArgs aa{};
    aa.nrels = GNR[g]; aa.nd = NT[d]; aa.pitch = GPITCH[g]; aa.abuf = ABUF;
    for (int i = 0; i < GNR[g]; i++) {
      int r = GRELS[g][i];
      aa.xsrc[i]   = XB0[REL_S[r]];
      aa.rowptr[i] = RP + rpoffByRel[r];
      aa.esrc[i]   = ESRC + (long)slotByRel[r] * E_EDGES;
    }
    aa.xsrc[GNR[g]] = XB0[d];
    hipLaunchKernelGGL(agg_kernel, dim3((NT[d] + 3) / 4, GNR[g] + 1), dim3(256), 0, stream, aa);
    mg(0,0,0, ABUF, WTG + gbaseT[g], BLS + g * 128, NWB, NT[d], GPITCH[g], GPITCH[g], 128);
    mg(0,0,1, NWB,  WTM1 + (long)g * 32768, mlp_b1 + d * 256, HIDB, NT[d], 128, 128, 256);
    mg(0,0,0, HIDB, WTM2 + (long)g * 32768, mlp_b2 + d * 128, MOUT, NT[d], 256, 256, 128);
    hipLaunchKernelGGL(xscatter_b, dim3(NT[d]), dim3(64), 0, stream,
                       mapin(d,0), mapin(d,1), MOUT, XB1[d], NT[d]);
  }

  // 5) CSR layer 1 (gene-dst relations only)
  static const int L1R[6] = {2, 4, 7, 9, 15, 17};
  int rpoff1[19];
  CsrArgs c1; c1.nslots = 6;
  {
    int co = 0, ro = 0;
    for (int s = 0; s < 6; s++) {
      int r = L1R[s];
      c1.relid[s] = r; c1.nd[s] = 15000; c1.cntoff[s] = co; c1.rpoff[s] = ro;
      rpoff1[r] = ro;
      co += 15000; ro += 15001;
    }
    hipMemsetAsync(CNT, 0, (size_t)co * 4, stream);
    hipLaunchKernelGGL(hist_kernel, dim3(391, 6), dim3(256), 0, stream, edges1, CNT, c1);
    hipLaunchKernelGGL(scan_kernel, dim3(6), dim3(256), 0, stream, CNT, RP, c1);
    hipMemcpyAsync(CUR, RP, (size_t)ro * 4, hipMemcpyDeviceToDevice, stream);
    hipLaunchKernelGGL(scatter_kernel, dim3(391, 6), dim3(256), 0, stream, edges1, CUR, ESRC, c1);
  }

  // 6) layer-1 gene conv: aggregate + GEMM -> G1 (fp32)
  {
    AggArgs aa{};
    aa.nrels = 6; aa.nd = 15000; aa.pitch = 896; aa.abuf = ABUF;
    for (int i = 0; i < 6; i++) {
      int r = L1R[i];
      aa.xsrc[i]   = XB1[REL_S[r]];
      aa.rowptr[i] = RP + rpoff1[r];
      aa.esrc[i]   = ESRC + (long)i * E_EDGES;
    }
    aa.xsrc[6] = XB1[1];
    hipLaunchKernelGGL(agg_kernel, dim3((15000 + 3) / 4, 7), dim3(256), 0, stream, aa);
    mg(0,1,0, ABUF, WTG + gbaseT[1], BLS + 1 * 128, G1, 15000, 896, 896, 128);
  }

  // 7) gene heads on proven fp32 vector GEMM
  hipLaunchKernelGGL(hgemm_kernel, dim3((15000 + 63) / 64, 2), dim3(256), 0, stream,
                     G1, gd_w1, gd_b1, HIDF, 15000, 128, 256);
  hipLaunchKernelGGL(head_reduce_kernel, dim3(15000), dim3(64), 0, stream,
                     HIDF, gd_w2, gd_b2, out, 0, 1);
  hipLaunchKernelGGL(hgemm_kernel, dim3((15000 + 63) / 64, 2), dim3(256), 0, stream,
                     G1, gv_w1, gv_b1, HIDF, 15000, 128, 256);
  hipLaunchKernelGGL(head_reduce_kernel, dim3(15000), dim3(64), 0, stream,
                     HIDF, gv_w2, gv_b2, out, 1, 0);
}

// Round 7
// 1107.116 us; speedup vs baseline: 4.1520x; 1.1231x over previous
//
#include <hip/hip_runtime.h>
#include <math.h>

#define E_EDGES 100000

typedef unsigned short u16;
typedef unsigned int u32;

using bfrag = __attribute__((ext_vector_type(8))) short;
using ffrag = __attribute__((ext_vector_type(4))) float;

__device__ inline float bf2f(u32 u) { union { u32 i; float f; } c; c.i = u << 16; return c.f; }
__device__ inline u16 f2bf(float f) {
  union { u32 i; float f; } c; c.f = f;
  u32 u = c.i;
  return (u16)((u + 0x7FFFu + ((u >> 16) & 1u)) >> 16);
}

// ---------------- structs ----------------
struct CsrArgs { int relid[24]; int lay[24]; int nd[24]; int cntoff[24]; int rpoff[24]; };

struct AggArgs {
  const u16* xsrc[7];   // per slot src table; slot nrels = xdst table
  const int* rowptr[6];
  const int* esrc[6];
  u16* abuf;
  int nrels, nd, pitch;
};

struct WTStackArgs {
  int srcrel[23];   // >=0: wl[r]; <0: sum-of-wr slot
  int grp[23];
  long outoff[23];
  int koff[23];
  int pitch[23];
  int gnr[5];
  int grel[5][6];
};

struct WTArgs { const float* W[15]; u16* out[15]; int K[15]; int N[15]; int Kpad[15]; };

struct F2BArgs { const float* s[6]; u16* d[6]; int n4[6]; };

struct InLinArgs { const float* A[5]; const u16* WT[5]; const float* bias[5]; u16* C[5];
                   int M[5]; int K[5]; int Kpad[5]; };

// ---------------- MFMA GEMM, m92-style: A and W^T both staged in LDS ----------------
// WT[n][k] row-major, row length Kpad, bf16, zero-padded. Block 256 = 4 waves;
// tile 64(M) x 128(N). A and B fragments use identical LDS read pattern.
template <int AF32, int OF32, int RELU>
__global__ __launch_bounds__(256) void tgemm(const void* __restrict__ Av,
                                             const u16* __restrict__ WT,
                                             const float* __restrict__ bias,
                                             void* __restrict__ Cv,
                                             int M, int K, int Kpad, int N)
{
  __shared__ u16 sA[64 * 40];
  __shared__ u16 sB[128 * 40];
  const int tid = threadIdx.x;
  const int w = tid >> 6, lane = tid & 63;
  const int quad = lane >> 4, m = lane & 15;
  const int rowbase = blockIdx.x * 64;
  const int colbase = blockIdx.y * 128;
  const int sr = tid >> 2, sc = tid & 3;
  const int br = tid >> 1, bh = tid & 1;
  ffrag acc[8];
  #pragma unroll
  for (int i = 0; i < 8; i++) { acc[i][0] = 0.f; acc[i][1] = 0.f; acc[i][2] = 0.f; acc[i][3] = 0.f; }

  for (int kt = 0; kt < Kpad / 32; kt++) {
    int gr = rowbase + sr, gk = kt * 32 + sc * 8;
    uint4 st = make_uint4(0, 0, 0, 0);
    if (AF32) {
      const float* A = (const float*)Av;
      if (gr < M) {
        const float* row = A + (long)gr * K + gk;
        float v[8];
        #pragma unroll
        for (int i = 0; i < 8; i++) v[i] = (gk + i < K) ? row[i] : 0.f;
        st.x = (u32)f2bf(v[0]) | ((u32)f2bf(v[1]) << 16);
        st.y = (u32)f2bf(v[2]) | ((u32)f2bf(v[3]) << 16);
        st.z = (u32)f2bf(v[4]) | ((u32)f2bf(v[5]) << 16);
        st.w = (u32)f2bf(v[6]) | ((u32)f2bf(v[7]) << 16);
      }
    } else {
      const u16* A = (const u16*)Av;
      if (gr < M) st = *(const uint4*)(A + (long)gr * K + gk);
    }
    const u16* wrow = WT + (long)(colbase + br) * Kpad + kt * 32 + bh * 16;
    uint4 b0 = *(const uint4*)wrow;
    uint4 b1 = *(const uint4*)(wrow + 8);

    if (kt) __syncthreads();
    *(uint4*)&sA[sr * 40 + sc * 8] = st;
    *(uint4*)&sB[br * 40 + bh * 16] = b0;
    *(uint4*)&sB[br * 40 + bh * 16 + 8] = b1;
    __syncthreads();

    bfrag a = *(const bfrag*)&sA[(w * 16 + m) * 40 + quad * 8];
    #pragma unroll
    for (int ct = 0; ct < 8; ct++) {
      bfrag b = *(const bfrag*)&sB[(ct * 16 + m) * 40 + quad * 8];
      acc[ct] = __builtin_amdgcn_mfma_f32_16x16x32_bf16(a, b, acc[ct], 0, 0, 0);
    }
  }

  #pragma unroll
  for (int ct = 0; ct < 8; ct++) {
    int col = colbase + ct * 16 + m;
    float bv = bias ? bias[col] : 0.f;
    #pragma unroll
    for (int r = 0; r < 4; r++) {
      int row = rowbase + w * 16 + quad * 4 + r;
      if (row < M) {
        float v = acc[ct][r] + bv;
        if (RELU) v = fmaxf(v, 0.f);
        long off = (long)row * N + col;
        if (OF32) ((float*)Cv)[off] = v;
        else ((u16*)Cv)[off] = f2bf(v);
      }
    }
  }
}

// ---------------- batched input linears (AF32, bf16 out, N=128) ----------------
__global__ __launch_bounds__(256) void tgemm_in(InLinArgs a)
{
  const int z = blockIdx.z;
  const int M = a.M[z], K = a.K[z], Kpad = a.Kpad[z];
  const int rowbase = blockIdx.x * 64;
  if (rowbase >= M) return;
  __shared__ u16 sA[64 * 40];
  __shared__ u16 sB[128 * 40];
  const int tid = threadIdx.x;
  const int w = tid >> 6, lane = tid & 63;
  const int quad = lane >> 4, m = lane & 15;
  const int sr = tid >> 2, sc = tid & 3;
  const int br = tid >> 1, bh = tid & 1;
  const float* A = a.A[z];
  const u16* WT = a.WT[z];
  ffrag acc[8];
  #pragma unroll
  for (int i = 0; i < 8; i++) { acc[i][0] = 0.f; acc[i][1] = 0.f; acc[i][2] = 0.f; acc[i][3] = 0.f; }

  for (int kt = 0; kt < Kpad / 32; kt++) {
    int gr = rowbase + sr, gk = kt * 32 + sc * 8;
    uint4 st = make_uint4(0, 0, 0, 0);
    if (gr < M) {
      const float* row = A + (long)gr * K + gk;
      float v[8];
      #pragma unroll
      for (int i = 0; i < 8; i++) v[i] = (gk + i < K) ? row[i] : 0.f;
      st.x = (u32)f2bf(v[0]) | ((u32)f2bf(v[1]) << 16);
      st.y = (u32)f2bf(v[2]) | ((u32)f2bf(v[3]) << 16);
      st.z = (u32)f2bf(v[4]) | ((u32)f2bf(v[5]) << 16);
      st.w = (u32)f2bf(v[6]) | ((u32)f2bf(v[7]) << 16);
    }
    const u16* wrow = WT + (long)br * Kpad + kt * 32 + bh * 16;
    uint4 b0 = *(const uint4*)wrow;
    uint4 b1 = *(const uint4*)(wrow + 8);

    if (kt) __syncthreads();
    *(uint4*)&sA[sr * 40 + sc * 8] = st;
    *(uint4*)&sB[br * 40 + bh * 16] = b0;
    *(uint4*)&sB[br * 40 + bh * 16 + 8] = b1;
    __syncthreads();

    bfrag av = *(const bfrag*)&sA[(w * 16 + m) * 40 + quad * 8];
    #pragma unroll
    for (int ct = 0; ct < 8; ct++) {
      bfrag bv = *(const bfrag*)&sB[(ct * 16 + m) * 40 + quad * 8];
      acc[ct] = __builtin_amdgcn_mfma_f32_16x16x32_bf16(av, bv, acc[ct], 0, 0, 0);
    }
  }

  const float* bias = a.bias[z];
  u16* C = a.C[z];
  #pragma unroll
  for (int ct = 0; ct < 8; ct++) {
    int col = ct * 16 + m;
    float bv = bias[col];
    #pragma unroll
    for (int r = 0; r < 4; r++) {
      int row = rowbase + w * 16 + quad * 4 + r;
      if (row < M) C[(long)row * 128 + col] = f2bf(acc[ct][r] + bv);
    }
  }
}

// ---------------- CSR build (combined L0+L1, slot-serialized 1-D grid) ----------------
__global__ __launch_bounds__(256) void hist_kernel(const int* __restrict__ e0,
                                                   const int* __restrict__ e1,
                                                   int* __restrict__ cnt, CsrArgs a)
{
  int slot = blockIdx.x / 391;
  int e = (blockIdx.x % 391) * 256 + threadIdx.x;
  if (e >= E_EDGES) return;
  const int* E = a.lay[slot] ? e1 : e0;
  int r = a.relid[slot];
  int dst = E[(r * 2 + 1) * E_EDGES + e];
  atomicAdd(&cnt[a.cntoff[slot] + dst], 1);
}

__global__ __launch_bounds__(256) void scan_kernel(const int* __restrict__ cnt,
                                                   int* __restrict__ rowptr, CsrArgs a)
{
  __shared__ int sbuf[256];
  int slot = blockIdx.x;
  int n = a.nd[slot], cb = a.cntoff[slot], rb = a.rpoff[slot];
  int tid = threadIdx.x;
  int carry = 0;
  for (int c0 = 0; c0 < n; c0 += 256) {
    int i = c0 + tid;
    int v = (i < n) ? cnt[cb + i] : 0;
    sbuf[tid] = v;
    __syncthreads();
    #pragma unroll
    for (int off = 1; off < 256; off <<= 1) {
      int t = (tid >= off) ? sbuf[tid - off] : 0;
      __syncthreads();
      sbuf[tid] += t;
      __syncthreads();
    }
    if (i < n) rowptr[rb + i] = carry + sbuf[tid] - v;
    carry += sbuf[255];
    __syncthreads();
  }
  if (tid == 0) rowptr[rb + n] = carry;
}

__global__ __launch_bounds__(256) void scatter_kernel(const int* __restrict__ e0,
                                                      const int* __restrict__ e1,
                                                      int* __restrict__ cursor,
                                                      int* __restrict__ esrc, CsrArgs a)
{
  int slot = blockIdx.x / 391;
  int e = (blockIdx.x % 391) * 256 + threadIdx.x;
  if (e >= E_EDGES) return;
  const int* E = a.lay[slot] ? e1 : e0;
  int r = a.relid[slot];
  int src = E[r * 2 * E_EDGES + e];
  int dst = E[(r * 2 + 1) * E_EDGES + e];
  int pos = atomicAdd(&cursor[a.rpoff[slot] + dst], 1);
  esrc[slot * E_EDGES + pos] = src;
}

// ---------------- stacked conv W^T (bf16) + bias sums ----------------
__global__ __launch_bounds__(256) void wtstack_kernel(const float* __restrict__ wl,
                                                      const float* __restrict__ wr,
                                                      const float* __restrict__ bl,
                                                      u16* __restrict__ WTG,
                                                      float* __restrict__ BLS, WTStackArgs a)
{
  int slot = blockIdx.y;
  int t = blockIdx.x * 256 + threadIdx.x;   // 0..16383
  int krel = t & 127, n = t >> 7;
  int sr = a.srcrel[slot];
  float v;
  if (sr >= 0) {
    v = wl[(long)sr * 16384 + krel * 128 + n];
  } else {
    int g = a.grp[slot];
    v = 0.f;
    for (int i = 0; i < a.gnr[g]; i++) v += wr[(long)a.grel[g][i] * 16384 + krel * 128 + n];
    if (t < 128) {
      float b = 0.f;
      for (int i = 0; i < a.gnr[g]; i++) b += bl[a.grel[g][i] * 128 + t];
      BLS[g * 128 + t] = b;
    }
  }
  WTG[a.outoff[slot] + (long)n * a.pitch[slot] + a.koff[slot] + krel] = f2bf(v);
}

// ---------------- generic W^T (batched): out[n*Kpad + k] = W[k][n] ----------------
__global__ __launch_bounds__(256) void wt_kernel(WTArgs a)
{
  int s = blockIdx.y;
  int idx = blockIdx.x * 256 + threadIdx.x;
  int K = a.K[s], N = a.N[s], Kpad = a.Kpad[s];
  if (idx >= N * Kpad) return;
  int n = idx / Kpad, k = idx - n * Kpad;
  a.out[s][idx] = (k < K) ? f2bf(a.W[s][(long)k * N + n]) : (u16)0;
}

// ---------------- batched fp32 -> bf16 convert ----------------
__global__ __launch_bounds__(256) void f2b_kernel(F2BArgs a)
{
  int s = blockIdx.y;
  int i = blockIdx.x * 256 + threadIdx.x;
  if (i >= a.n4[s]) return;
  float4 v = ((const float4*)a.s[s])[i];
  ushort4 o; o.x = f2bf(v.x); o.y = f2bf(v.y); o.z = f2bf(v.z); o.w = f2bf(v.w);
  ((ushort4*)a.d[s])[i] = o;
}

// ---------------- aggregation: one wave per (dst row, relation slot) ----------------
__global__ __launch_bounds__(256) void agg_kernel(AggArgs a)
{
  int slot = blockIdx.y;
  int wave = threadIdx.x >> 6, lane = threadIdx.x & 63;
  int row = blockIdx.x * 4 + wave;
  if (row >= a.nd) return;
  u16* dst = a.abuf + (long)row * a.pitch + slot * 128 + lane * 2;
  const u32* x2 = (const u32*)a.xsrc[slot];
  if (slot == a.nrels) {          // x_dst passthrough slot
    *(u32*)dst = x2[(long)row * 64 + lane];
    return;
  }
  const int* rp = a.rowptr[slot];
  int c0 = rp[row], c1 = rp[row + 1];
  const int* es = a.esrc[slot];
  float ax = 0.f, ay = 0.f;
  int e = c0;
  for (; e + 4 <= c1; e += 4) {
    int s0 = es[e], s1 = es[e + 1], s2 = es[e + 2], s3 = es[e + 3];
    u32 v0 = x2[(long)s0 * 64 + lane];
    u32 v1 = x2[(long)s1 * 64 + lane];
    u32 v2 = x2[(long)s2 * 64 + lane];
    u32 v3 = x2[(long)s3 * 64 + lane];
    ax += bf2f(v0 & 0xFFFF) + bf2f(v1 & 0xFFFF) + bf2f(v2 & 0xFFFF) + bf2f(v3 & 0xFFFF);
    ay += bf2f(v0 >> 16) + bf2f(v1 >> 16) + bf2f(v2 >> 16) + bf2f(v3 >> 16);
  }
  for (; e < c1; e++) {
    u32 v = x2[(long)es[e] * 64 + lane];
    ax += bf2f(v & 0xFFFF);
    ay += bf2f(v >> 16);
  }
  int c = c1 - c0;
  float inv = 1.f / (float)(c > 1 ? c : 1);
  ax *= inv; ay *= inv;
  *(u32*)dst = (u32)f2bf(ax) | ((u32)f2bf(ay) << 16);
}

// ---------------- cross-layer scatter (bf16 rows, binary search on sorted ids) --------
__global__ __launch_bounds__(64) void xscatter_b(const int* __restrict__ map0,
                                                 const int* __restrict__ map1,
                                                 const u16* __restrict__ src,
                                                 u16* __restrict__ dst, int n)
{
  __shared__ int spos;
  int j = blockIdx.x;
  if (threadIdx.x == 0) {
    int key = map1[j];
    int lo = 0, hi = n - 1, pos = -1;
    while (lo <= hi) {
      int mid = (lo + hi) >> 1;
      int v = map0[mid];
      if (v == key) { pos = mid; break; }
      if (v < key) lo = mid + 1; else hi = mid - 1;
    }
    spos = pos;
  }
  __syncthreads();
  int p = spos;
  if (p >= 0)
    ((u32*)dst)[(long)j * 64 + threadIdx.x] = ((const u32*)src)[(long)p * 64 + threadIdx.x];
}

// ---------------- head: out[row*2+col] = post(hid[row,:256] . w2 + b2) ----------------
__global__ __launch_bounds__(64) void head_reduce_kernel(const float* __restrict__ hid,
                                                         const float* __restrict__ w2,
                                                         const float* __restrict__ b2,
                                                         float* __restrict__ out,
                                                         int col, int dosig)
{
  int row = blockIdx.x;
  int lane = threadIdx.x;
  const float* h = hid + (long)row * 256;
  float s = h[lane] * w2[lane] + h[lane + 64] * w2[lane + 64]
          + h[lane + 128] * w2[lane + 128] + h[lane + 192] * w2[lane + 192];
  #pragma unroll
  for (int off = 32; off >= 1; off >>= 1) s += __shfl_down(s, off, 64);
  if (lane == 0) {
    float v = s + b2[0];
    if (dosig) v = 1.0f / (1.0f + expf(-v));
    out[row * 2 + col] = v;
  }
}

// ---------------- host orchestration ----------------
extern "C" void kernel_launch(void* const* d_in, const int* in_sizes, int n_in,
                              void* d_out, int out_size, void* d_ws, size_t ws_size,
                              hipStream_t stream)
{
  static const int NT[6] = {25000, 15000, 4000, 12000, 12000, 15000};
  static const int REL_S[19] = {2,0,2,1,0,1,3,3,1,3,1,3,4,5,0,5,1,0,1};
  static const int REL_D[19] = {0,2,1,2,1,0,3,1,3,1,3,4,3,0,5,1,5,1,0};

  auto xin   = [&](int t, int L) { return (const float*)d_in[L * 13 + 2 * t]; };
  auto mapin = [&](int t, int L) { return (const int*)d_in[L * 13 + 2 * t + 1]; };
  const int* edges0 = (const int*)d_in[12];
  const int* edges1 = (const int*)d_in[25];
  const float* W_in_atac  = (const float*)d_in[26];
  const float* b_in_atac  = (const float*)d_in[27];
  const float* W_in_gene  = (const float*)d_in[28];
  const float* b_in_gene  = (const float*)d_in[29];
  const float* W_in_pname = (const float*)d_in[30];
  const float* b_in_pname = (const float*)d_in[31];
  const float* conv_wl = (const float*)d_in[32];
  const float* conv_bl = (const float*)d_in[33];
  const float* conv_wr = (const float*)d_in[34];
  const float* mlp_w1 = (const float*)d_in[35];
  const float* mlp_b1 = (const float*)d_in[36];
  const float* mlp_w2 = (const float*)d_in[37];
  const float* mlp_b2 = (const float*)d_in[38];
  const float* gd_w1 = (const float*)d_in[39];
  const float* gd_b1 = (const float*)d_in[40];
  const float* gd_w2 = (const float*)d_in[41];
  const float* gd_b2 = (const float*)d_in[42];
  const float* gv_w1 = (const float*)d_in[43];
  const float* gv_b1 = (const float*)d_in[44];
  const float* gv_w2 = (const float*)d_in[45];
  const float* gv_b2 = (const float*)d_in[46];
  float* out = (float*)d_out;

  // ---- workspace carve (~136 MB): fp32, bf16, int sections ----
  float* fp = (float*)d_ws;
  auto takef = [&](size_t n) { float* q = fp; fp += n; return q; };
  float* BLS  = takef(5 * 128);
  float* G1   = takef((size_t)15000 * 128);
  float* HIDF = takef((size_t)15000 * 256);
  u16* bp = (u16*)fp;
  auto takeb = [&](size_t n) { u16* q = bp; bp += n; return q; };
  u16* XB0[6]; u16* XB1[6];
  XB0[0] = takeb((size_t)25000 * 128);
  XB0[1] = takeb((size_t)15000 * 128);
  XB0[2] = takeb((size_t)4000 * 128);
  XB0[3] = takeb((size_t)12000 * 128);
  XB0[4] = takeb((size_t)12000 * 128);
  XB0[5] = takeb((size_t)15000 * 128);
  XB1[0] = takeb((size_t)25000 * 128);
  XB1[1] = takeb((size_t)15000 * 128);
  XB1[2] = takeb((size_t)4000 * 128);
  XB1[3] = takeb((size_t)12000 * 128);
  XB1[4] = nullptr;
  XB1[5] = takeb((size_t)15000 * 128);
  u16* ABUF = takeb((size_t)16000000);       // = 25000*640; >= 15000*896
  u16* NWB  = takeb((size_t)25000 * 128);
  u16* HIDB = takeb((size_t)25000 * 256);
  u16* MOUT = takeb((size_t)25000 * 128);
  u16* WTG  = takeb(376832);
  u16* WTIA = takeb(128 * 288);
  u16* WTIG = takeb(128 * 160);
  u16* WTIP = takeb(128 * 160);
  u16* WTM1 = takeb((size_t)5 * 32768);
  u16* WTM2 = takeb((size_t)5 * 32768);
  u16* WTHD = takeb(32768);                  // gd_w1^T: 256 x 128
  u16* WTHV = takeb(32768);
  uintptr_t ipa = ((uintptr_t)bp + 15) & ~(uintptr_t)15;
  int* ip = (int*)ipa;
  auto takei = [&](size_t n) { int* q = ip; ip += n; return q; };
  int* CNT  = takei(366000);
  int* RP   = takei(366024);
  int* CUR  = takei(366024);
  int* ESRC = takei((size_t)24 * E_EDGES);

  // dst-type groups
  static const int GD[5]       = {0, 1, 2, 3, 5};
  static const int GNR[5]      = {4, 6, 2, 4, 2};
  static const int GRELS[5][6] = {{0,5,13,18,0,0},{2,4,7,9,15,17},{1,3,0,0,0,0},
                                  {6,8,10,12,0,0},{14,16,0,0,0,0}};
  static const int GPITCH[5]   = {640, 896, 384, 640, 384};
  long gbaseT[5];
  {
    long o = 0;
    for (int g = 0; g < 5; g++) { gbaseT[g] = o; o += (long)128 * GPITCH[g]; }
  }

  // 1) build transposed weights
  {
    WTStackArgs wa{};
    int j = 0;
    for (int g = 0; g < 5; g++) {
      wa.gnr[g] = GNR[g];
      for (int i = 0; i < 6; i++) wa.grel[g][i] = GRELS[g][i];
      for (int s = 0; s <= GNR[g]; s++, j++) {
        wa.srcrel[j] = (s < GNR[g]) ? GRELS[g][s] : -1;
        wa.grp[j] = g;
        wa.outoff[j] = gbaseT[g];
        wa.koff[j] = s * 128;
        wa.pitch[j] = GPITCH[g];
      }
    }
    hipLaunchKernelGGL(wtstack_kernel, dim3(64, 23), dim3(256), 0, stream,
                       conv_wl, conv_wr, conv_bl, WTG, BLS, wa);
  }
  {
    WTArgs pa{};
    int s = 0;
    auto add = [&](const float* W, u16* o, int K, int N, int Kpad) {
      pa.W[s] = W; pa.out[s] = o; pa.K[s] = K; pa.N[s] = N; pa.Kpad[s] = Kpad; s++;
    };
    add(W_in_atac,  WTIA, 257, 128, 288);
    add(W_in_gene,  WTIG, 129, 128, 160);
    add(W_in_pname, WTIP, 129, 128, 160);
    for (int g = 0; g < 5; g++) {
      int d = GD[g];
      add(mlp_w1 + (long)d * 128 * 256, WTM1 + (long)g * 32768, 128, 256, 128);
      add(mlp_w2 + (long)d * 256 * 128, WTM2 + (long)g * 32768, 256, 128, 256);
    }
    add(gd_w1, WTHD, 128, 256, 128);
    add(gv_w1, WTHV, 128, 256, 128);
    hipLaunchKernelGGL(wt_kernel, dim3(144, 15), dim3(256), 0, stream, pa);
  }

  auto mg = [&](int af32, int of32, int relu, const void* A, const u16* WT,
                const float* b, void* C, int M, int K, int Kpad, int N) {
    dim3 grid((M + 63) / 64, N / 128);
    if (af32) {
      if (of32 && relu) hipLaunchKernelGGL(HIP_KERNEL_NAME(tgemm<1,1,1>), grid, dim3(256), 0, stream, A, WT, b, C, M, K, Kpad, N);
      else              hipLaunchKernelGGL(HIP_KERNEL_NAME(tgemm<1,0,0>), grid, dim3(256), 0, stream, A, WT, b, C, M, K, Kpad, N);
    } else {
      if (of32)      hipLaunchKernelGGL(HIP_KERNEL_NAME(tgemm<0,1,0>), grid, dim3(256), 0, stream, A, WT, b, C, M, K, Kpad, N);
      else if (relu) hipLaunchKernelGGL(HIP_KERNEL_NAME(tgemm<0,0,1>), grid, dim3(256), 0, stream, A, WT, b, C, M, K, Kpad, N);
      else           hipLaunchKernelGGL(HIP_KERNEL_NAME(tgemm<0,0,0>), grid, dim3(256), 0, stream, A, WT, b, C, M, K, Kpad, N);
    }
  };

  // 2) input linears (batched) + raw-table converts (batched)
  {
    InLinArgs ia{};
    auto add = [&](int s, const float* A, const u16* WT, const float* b, u16* C,
                   int M, int K, int Kpad) {
      ia.A[s] = A; ia.WT[s] = WT; ia.bias[s] = b; ia.C[s] = C;
      ia.M[s] = M; ia.K[s] = K; ia.Kpad[s] = Kpad;
    };
    add(0, xin(0,0), WTIA, b_in_atac,  XB0[0], 25000, 257, 288);
    add(1, xin(1,0), WTIG, b_in_gene,  XB0[1], 15000, 129, 160);
    add(2, xin(4,0), WTIP, b_in_pname, XB0[4], 12000, 129, 160);
    add(3, xin(0,1), WTIA, b_in_atac,  XB1[0], 25000, 257, 288);
    add(4, xin(1,1), WTIG, b_in_gene,  XB1[1], 15000, 129, 160);
    hipLaunchKernelGGL(tgemm_in, dim3(391, 1, 5), dim3(256), 0, stream, ia);
  }
  {
    F2BArgs fa{};
    const float* ss[6] = {xin(2,0), xin(3,0), xin(5,0), xin(2,1), xin(3,1), xin(5,1)};
    u16* dd[6] = {XB0[2], XB0[3], XB0[5], XB1[2], XB1[3], XB1[5]};
    int nn[6] = {4000*32, 12000*32, 15000*32, 4000*32, 12000*32, 15000*32};
    for (int s = 0; s < 6; s++) { fa.s[s] = ss[s]; fa.d[s] = dd[s]; fa.n4[s] = nn[s]; }
    hipLaunchKernelGGL(f2b_kernel, dim3(1875, 6), dim3(256), 0, stream, fa);
  }

  // 3) CSR build, combined L0 (18 slots) + L1 (6 slots), slot-serialized
  static const int L0R[18] = {0,1,2,3,4,5,6,7,8,9,10,12,13,14,15,16,17,18};
  static const int L1R[6]  = {2, 4, 7, 9, 15, 17};
  int rpoffByRel[19], slotByRel[19], rpoff1[19], slot1[19];
  CsrArgs cc{};
  {
    int co = 0, ro = 0, s = 0;
    for (int i = 0; i < 18; i++, s++) {
      int r = L0R[i];
      cc.relid[s] = r; cc.lay[s] = 0; int nd = NT[REL_D[r]];
      cc.nd[s] = nd; cc.cntoff[s] = co; cc.rpoff[s] = ro;
      rpoffByRel[r] = ro; slotByRel[r] = s;
      co += nd; ro += nd + 1;
    }
    for (int i = 0; i < 6; i++, s++) {
      int r = L1R[i];
      cc.relid[s] = r; cc.lay[s] = 1;
      cc.nd[s] = 15000; cc.cntoff[s] = co; cc.rpoff[s] = ro;
      rpoff1[r] = ro; slot1[r] = s;
      co += 15000; ro += 15001;
    }
    hipMemsetAsync(CNT, 0, (size_t)co * 4, stream);
    hipLaunchKernelGGL(hist_kernel, dim3(24 * 391), dim3(256), 0, stream, edges0, edges1, CNT, cc);
    hipLaunchKernelGGL(scan_kernel, dim3(24), dim3(256), 0, stream, CNT, RP, cc);
    hipMemcpyAsync(CUR, RP, (size_t)ro * 4, hipMemcpyDeviceToDevice, stream);
    hipLaunchKernelGGL(scatter_kernel, dim3(24 * 391), dim3(256), 0, stream, edges0, edges1, CUR, ESRC, cc);
  }

  // 4) per dst group: aggregate -> conv GEMM -> MLP -> scatter into layer-1 tables
  for (int g = 0; g < 5; g++) {
    int d = GD[g];
    AggArgs aa{};
    aa.nrels = GNR[g]; aa.nd = NT[d]; aa.pitch = GPITCH[g]; aa.abuf = ABUF;
    for (int i = 0; i < GNR[g]; i++) {
      int r = GRELS[g][i];
      aa.xsrc[i]   = XB0[REL_S[r]];
      aa.rowptr[i] = RP + rpoffByRel[r];
      aa.esrc[i]   = ESRC + (long)slotByRel[r] * E_EDGES;
    }
    aa.xsrc[GNR[g]] = XB0[d];
    hipLaunchKernelGGL(agg_kernel, dim3((NT[d] + 3) / 4, GNR[g] + 1), dim3(256), 0, stream, aa);
    mg(0,0,0, ABUF, WTG + gbaseT[g], BLS + g * 128, NWB, NT[d], GPITCH[g], GPITCH[g], 128);
    mg(0,0,1, NWB,  WTM1 + (long)g * 32768, mlp_b1 + d * 256, HIDB, NT[d], 128, 128, 256);
    mg(0,0,0, HIDB, WTM2 + (long)g * 32768, mlp_b2 + d * 128, MOUT, NT[d], 256, 256, 128);
    hipLaunchKernelGGL(xscatter_b, dim3(NT[d]), dim3(64), 0, stream,
                       mapin(d,0), mapin(d,1), MOUT, XB1[d], NT[d]);
  }

  // 6) layer-1 gene conv: aggregate + GEMM -> G1 (fp32)
  {
    AggArgs aa{};
    aa.nrels = 6; aa.nd = 15000; aa.pitch = 896; aa.abuf = ABUF;
    for (int i = 0; i < 6; i++) {
      int r = L1R[i];
      aa.xsrc[i]   = XB1[REL_S[r]];
      aa.rowptr[i] = RP + rpoff1[r];
      aa.esrc[i]   = ESRC + (long)slot1[r] * E_EDGES;
    }
    aa.xsrc[6] = XB1[1];
    hipLaunchKernelGGL(agg_kernel, dim3((15000 + 3) / 4, 7), dim3(256), 0, stream, aa);
    mg(0,1,0, ABUF, WTG + gbaseT[1], BLS + 1 * 128, G1, 15000, 896, 896, 128);
  }

  // 7) gene heads on MFMA (fp32 in/out, relu) + reduce
  mg(1,1,1, G1, WTHD, gd_b1, HIDF, 15000, 128, 128, 256);
  hipLaunchKernelGGL(head_reduce_kernel, dim3(15000), dim3(64), 0, stream,
                     HIDF, gd_w2, gd_b2, out, 0, 1);
  mg(1,1,1, G1, WTHV, gv_b1, HIDF, 15000, 128, 128, 256);
  hipLaunchKernelGGL(head_reduce_kernel, dim3(15000), dim3(64), 0, stream,
                     HIDF, gv_w2, gv_b2, out, 1, 0);
}

// Round 8
// 862.855 us; speedup vs baseline: 5.3274x; 1.2831x over previous
//
#include <hip/hip_runtime.h>
#include <math.h>

#define E_EDGES 100000

typedef unsigned short u16;
typedef unsigned int u32;

using bfrag = __attribute__((ext_vector_type(8))) short;
using ffrag = __attribute__((ext_vector_type(4))) float;

__device__ inline float bf2f(u32 u) { union { u32 i; float f; } c; c.i = u << 16; return c.f; }
__device__ inline u16 f2bf(float f) {
  union { u32 i; float f; } c; c.f = f;
  u32 u = c.i;
  return (u16)((u + 0x7FFFu + ((u >> 16) & 1u)) >> 16);
}

// ---------------- structs ----------------
struct CsrArgs { int relid[24]; int lay[24]; int nd[24]; int cntoff[24]; int rpoff[24];
                 int bkoff[24]; int nb[24]; };

struct AggArgs {
  const u16* xsrc[7];
  const int* rowptr[6];
  const int* esrc[6];
  u16* abuf;
  int nrels, nd, pitch;
};

struct WTStackArgs {
  int srcrel[23]; int grp[23]; long outoff[23]; int koff[23]; int pitch[23];
  int gnr[5]; int grel[5][6];
};

struct WTArgs { const float* W[15]; u16* out[15]; int K[15]; int N[15]; int Kpad[15]; };
struct F2BArgs { const float* s[6]; u16* d[6]; int n4[6]; };
struct InLinArgs { const float* A[5]; const u16* WT[5]; const float* bias[5]; u16* C[5];
                   int M[5]; int K[5]; int Kpad[5]; };
struct PosArgs { const int* m0[5]; const int* m1[5]; int* pos[5]; int n[5]; };
struct HeadArgs { const u16* WT[2]; const float* b1[2]; float* hid[2]; const float* A; int M; };
struct HeadRArgs { const float* hid[2]; const float* w2[2]; const float* b2[2]; float* out; };

// ---------------- MFMA GEMM (verified R6 structure) ----------------
template <int AF32, int OF32, int RELU>
__global__ __launch_bounds__(256) void tgemm(const void* __restrict__ Av,
                                             const u16* __restrict__ WT,
                                             const float* __restrict__ bias,
                                             void* __restrict__ Cv,
                                             int M, int K, int Kpad, int N)
{
  __shared__ u16 sA[64 * 40];
  __shared__ u16 sB[128 * 40];
  const int tid = threadIdx.x;
  const int w = tid >> 6, lane = tid & 63;
  const int quad = lane >> 4, m = lane & 15;
  const int rowbase = blockIdx.x * 64;
  const int colbase = blockIdx.y * 128;
  const int sr = tid >> 2, sc = tid & 3;
  const int br = tid >> 1, bh = tid & 1;
  ffrag acc[8];
  #pragma unroll
  for (int i = 0; i < 8; i++) { acc[i][0] = 0.f; acc[i][1] = 0.f; acc[i][2] = 0.f; acc[i][3] = 0.f; }

  for (int kt = 0; kt < Kpad / 32; kt++) {
    int gr = rowbase + sr, gk = kt * 32 + sc * 8;
    uint4 st = make_uint4(0, 0, 0, 0);
    if (AF32) {
      const float* A = (const float*)Av;
      if (gr < M) {
        const float* row = A + (long)gr * K + gk;
        float v[8];
        #pragma unroll
        for (int i = 0; i < 8; i++) v[i] = (gk + i < K) ? row[i] : 0.f;
        st.x = (u32)f2bf(v[0]) | ((u32)f2bf(v[1]) << 16);
        st.y = (u32)f2bf(v[2]) | ((u32)f2bf(v[3]) << 16);
        st.z = (u32)f2bf(v[4]) | ((u32)f2bf(v[5]) << 16);
        st.w = (u32)f2bf(v[6]) | ((u32)f2bf(v[7]) << 16);
      }
    } else {
      const u16* A = (const u16*)Av;
      if (gr < M) st = *(const uint4*)(A + (long)gr * K + gk);
    }
    const u16* wrow = WT + (long)(colbase + br) * Kpad + kt * 32 + bh * 16;
    uint4 b0 = *(const uint4*)wrow;
    uint4 b1 = *(const uint4*)(wrow + 8);

    if (kt) __syncthreads();
    *(uint4*)&sA[sr * 40 + sc * 8] = st;
    *(uint4*)&sB[br * 40 + bh * 16] = b0;
    *(uint4*)&sB[br * 40 + bh * 16 + 8] = b1;
    __syncthreads();

    bfrag a = *(const bfrag*)&sA[(w * 16 + m) * 40 + quad * 8];
    #pragma unroll
    for (int ct = 0; ct < 8; ct++) {
      bfrag b = *(const bfrag*)&sB[(ct * 16 + m) * 40 + quad * 8];
      acc[ct] = __builtin_amdgcn_mfma_f32_16x16x32_bf16(a, b, acc[ct], 0, 0, 0);
    }
  }

  #pragma unroll
  for (int ct = 0; ct < 8; ct++) {
    int col = colbase + ct * 16 + m;
    float bv = bias ? bias[col] : 0.f;
    #pragma unroll
    for (int r = 0; r < 4; r++) {
      int row = rowbase + w * 16 + quad * 4 + r;
      if (row < M) {
        float v = acc[ct][r] + bv;
        if (RELU) v = fmaxf(v, 0.f);
        long off = (long)row * N + col;
        if (OF32) ((float*)Cv)[off] = v;
        else ((u16*)Cv)[off] = f2bf(v);
      }
    }
  }
}

// ---------------- mlp2 GEMM with fused row-permute scatter (bf16 A, bf16 out) --------
__global__ __launch_bounds__(256) void tgemm_scat(const u16* __restrict__ A,
                                                  const u16* __restrict__ WT,
                                                  const float* __restrict__ bias,
                                                  const int* __restrict__ POS,
                                                  u16* __restrict__ C,
                                                  int M, int Kpad)
{
  __shared__ u16 sA[64 * 40];
  __shared__ u16 sB[128 * 40];
  const int tid = threadIdx.x;
  const int w = tid >> 6, lane = tid & 63;
  const int quad = lane >> 4, m = lane & 15;
  const int rowbase = blockIdx.x * 64;
  const int sr = tid >> 2, sc = tid & 3;
  const int br = tid >> 1, bh = tid & 1;
  ffrag acc[8];
  #pragma unroll
  for (int i = 0; i < 8; i++) { acc[i][0] = 0.f; acc[i][1] = 0.f; acc[i][2] = 0.f; acc[i][3] = 0.f; }

  for (int kt = 0; kt < Kpad / 32; kt++) {
    int gr = rowbase + sr, gk = kt * 32 + sc * 8;
    uint4 st = make_uint4(0, 0, 0, 0);
    if (gr < M) st = *(const uint4*)(A + (long)gr * Kpad + gk);
    const u16* wrow = WT + (long)br * Kpad + kt * 32 + bh * 16;
    uint4 b0 = *(const uint4*)wrow;
    uint4 b1 = *(const uint4*)(wrow + 8);

    if (kt) __syncthreads();
    *(uint4*)&sA[sr * 40 + sc * 8] = st;
    *(uint4*)&sB[br * 40 + bh * 16] = b0;
    *(uint4*)&sB[br * 40 + bh * 16 + 8] = b1;
    __syncthreads();

    bfrag a = *(const bfrag*)&sA[(w * 16 + m) * 40 + quad * 8];
    #pragma unroll
    for (int ct = 0; ct < 8; ct++) {
      bfrag b = *(const bfrag*)&sB[(ct * 16 + m) * 40 + quad * 8];
      acc[ct] = __builtin_amdgcn_mfma_f32_16x16x32_bf16(a, b, acc[ct], 0, 0, 0);
    }
  }

  #pragma unroll
  for (int ct = 0; ct < 8; ct++) {
    int col = ct * 16 + m;
    float bv = bias[col];
    #pragma unroll
    for (int r = 0; r < 4; r++) {
      int row = rowbase + w * 16 + quad * 4 + r;
      if (row < M) {
        int j = POS[row];
        if (j >= 0) C[(long)j * 128 + col] = f2bf(acc[ct][r] + bv);
      }
    }
  }
}

// ---------------- batched input linears ----------------
__global__ __launch_bounds__(256) void tgemm_in(InLinArgs a)
{
  const int z = blockIdx.z;
  const int M = a.M[z], K = a.K[z], Kpad = a.Kpad[z];
  const int rowbase = blockIdx.x * 64;
  if (rowbase >= M) return;
  __shared__ u16 sA[64 * 40];
  __shared__ u16 sB[128 * 40];
  const int tid = threadIdx.x;
  const int w = tid >> 6, lane = tid & 63;
  const int quad = lane >> 4, m = lane & 15;
  const int sr = tid >> 2, sc = tid & 3;
  const int br = tid >> 1, bh = tid & 1;
  const float* A = a.A[z];
  const u16* WT = a.WT[z];
  ffrag acc[8];
  #pragma unroll
  for (int i = 0; i < 8; i++) { acc[i][0] = 0.f; acc[i][1] = 0.f; acc[i][2] = 0.f; acc[i][3] = 0.f; }

  for (int kt = 0; kt < Kpad / 32; kt++) {
    int gr = rowbase + sr, gk = kt * 32 + sc * 8;
    uint4 st = make_uint4(0, 0, 0, 0);
    if (gr < M) {
      const float* row = A + (long)gr * K + gk;
      float v[8];
      #pragma unroll
      for (int i = 0; i < 8; i++) v[i] = (gk + i < K) ? row[i] : 0.f;
      st.x = (u32)f2bf(v[0]) | ((u32)f2bf(v[1]) << 16);
      st.y = (u32)f2bf(v[2]) | ((u32)f2bf(v[3]) << 16);
      st.z = (u32)f2bf(v[4]) | ((u32)f2bf(v[5]) << 16);
      st.w = (u32)f2bf(v[6]) | ((u32)f2bf(v[7]) << 16);
    }
    const u16* wrow = WT + (long)br * Kpad + kt * 32 + bh * 16;
    uint4 b0 = *(const uint4*)wrow;
    uint4 b1 = *(const uint4*)(wrow + 8);

    if (kt) __syncthreads();
    *(uint4*)&sA[sr * 40 + sc * 8] = st;
    *(uint4*)&sB[br * 40 + bh * 16] = b0;
    *(uint4*)&sB[br * 40 + bh * 16 + 8] = b1;
    __syncthreads();

    bfrag av = *(const bfrag*)&sA[(w * 16 + m) * 40 + quad * 8];
    #pragma unroll
    for (int ct = 0; ct < 8; ct++) {
      bfrag bv = *(const bfrag*)&sB[(ct * 16 + m) * 40 + quad * 8];
      acc[ct] = __builtin_amdgcn_mfma_f32_16x16x32_bf16(av, bv, acc[ct], 0, 0, 0);
    }
  }

  const float* bias = a.bias[z];
  u16* C = a.C[z];
  #pragma unroll
  for (int ct = 0; ct < 8; ct++) {
    int col = ct * 16 + m;
    float bv = bias[col];
    #pragma unroll
    for (int r = 0; r < 4; r++) {
      int row = rowbase + w * 16 + quad * 4 + r;
      if (row < M) C[(long)row * 128 + col] = f2bf(acc[ct][r] + bv);
    }
  }
}

// ---------------- batched gene heads (fp32 A, fp32 out, relu, N=256) ----------------
__global__ __launch_bounds__(256) void tgemm_head(HeadArgs a)
{
  const int z = blockIdx.z;
  const int M = a.M;
  const int rowbase = blockIdx.x * 64;
  const int colbase = blockIdx.y * 128;
  __shared__ u16 sA[64 * 40];
  __shared__ u16 sB[128 * 40];
  const int tid = threadIdx.x;
  const int w = tid >> 6, lane = tid & 63;
  const int quad = lane >> 4, m = lane & 15;
  const int sr = tid >> 2, sc = tid & 3;
  const int br = tid >> 1, bh = tid & 1;
  const float* A = a.A;
  const u16* WT = a.WT[z];
  ffrag acc[8];
  #pragma unroll
  for (int i = 0; i < 8; i++) { acc[i][0] = 0.f; acc[i][1] = 0.f; acc[i][2] = 0.f; acc[i][3] = 0.f; }

  for (int kt = 0; kt < 4; kt++) {
    int gr = rowbase + sr, gk = kt * 32 + sc * 8;
    uint4 st = make_uint4(0, 0, 0, 0);
    if (gr < M) {
      const float* row = A + (long)gr * 128 + gk;
      float v[8];
      #pragma unroll
      for (int i = 0; i < 8; i++) v[i] = row[i];
      st.x = (u32)f2bf(v[0]) | ((u32)f2bf(v[1]) << 16);
      st.y = (u32)f2bf(v[2]) | ((u32)f2bf(v[3]) << 16);
      st.z = (u32)f2bf(v[4]) | ((u32)f2bf(v[5]) << 16);
      st.w = (u32)f2bf(v[6]) | ((u32)f2bf(v[7]) << 16);
    }
    const u16* wrow = WT + (long)(colbase + br) * 128 + kt * 32 + bh * 16;
    uint4 b0 = *(const uint4*)wrow;
    uint4 b1 = *(const uint4*)(wrow + 8);

    if (kt) __syncthreads();
    *(uint4*)&sA[sr * 40 + sc * 8] = st;
    *(uint4*)&sB[br * 40 + bh * 16] = b0;
    *(uint4*)&sB[br * 40 + bh * 16 + 8] = b1;
    __syncthreads();

    bfrag av = *(const bfrag*)&sA[(w * 16 + m) * 40 + quad * 8];
    #pragma unroll
    for (int ct = 0; ct < 8; ct++) {
      bfrag bv = *(const bfrag*)&sB[(ct * 16 + m) * 40 + quad * 8];
      acc[ct] = __builtin_amdgcn_mfma_f32_16x16x32_bf16(av, bv, acc[ct], 0, 0, 0);
    }
  }

  const float* bias = a.b1[z];
  float* C = a.hid[z];
  #pragma unroll
  for (int ct = 0; ct < 8; ct++) {
    int col = colbase + ct * 16 + m;
    float bv = bias[col];
    #pragma unroll
    for (int r = 0; r < 4; r++) {
      int row = rowbase + w * 16 + quad * 4 + r;
      if (row < M) C[(long)row * 256 + col] = fmaxf(acc[ct][r] + bv, 0.f);
    }
  }
}

// ---------------- CSR build ----------------
__global__ __launch_bounds__(256) void hist_kernel(const int* __restrict__ e0,
                                                   const int* __restrict__ e1,
                                                   int* __restrict__ cnt, CsrArgs a)
{
  int slot = blockIdx.x / 391;
  int e = (blockIdx.x % 391) * 256 + threadIdx.x;
  if (e >= E_EDGES) return;
  const int* E = a.lay[slot] ? e1 : e0;
  int r = a.relid[slot];
  int dst = E[(r * 2 + 1) * E_EDGES + e];
  atomicAdd(&cnt[a.cntoff[slot] + dst], 1);
}

// wave-shuffle scan: 1024 elems/iter, 2 barriers/iter
__global__ __launch_bounds__(256) void scan_kernel(const int* __restrict__ cnt,
                                                   int* __restrict__ rowptr, CsrArgs a)
{
  int slot = blockIdx.x;
  int n = a.nd[slot], cb = a.cntoff[slot], rb = a.rpoff[slot];
  int tid = threadIdx.x, lane = tid & 63, w = tid >> 6;
  __shared__ int wsum[4];
  int carry = 0;
  for (int c0 = 0; c0 < n; c0 += 1024) {
    int idx = c0 + tid * 4;
    int v0 = (idx     < n) ? cnt[cb + idx]     : 0;
    int v1 = (idx + 1 < n) ? cnt[cb + idx + 1] : 0;
    int v2 = (idx + 2 < n) ? cnt[cb + idx + 2] : 0;
    int v3 = (idx + 3 < n) ? cnt[cb + idx + 3] : 0;
    int s = v0 + v1 + v2 + v3;
    int si = s;
    #pragma unroll
    for (int off = 1; off < 64; off <<= 1) {
      int t = __shfl_up(si, off, 64);
      if (lane >= off) si += t;
    }
    if (lane == 63) wsum[w] = si;
    __syncthreads();
    int woff = 0;
    #pragma unroll
    for (int k = 0; k < 4; k++) if (k < w) woff += wsum[k];
    int tot = wsum[0] + wsum[1] + wsum[2] + wsum[3];
    int e = carry + woff + (si - s);
    if (idx     < n) rowptr[rb + idx]     = e;
    if (idx + 1 < n) rowptr[rb + idx + 1] = e + v0;
    if (idx + 2 < n) rowptr[rb + idx + 2] = e + v0 + v1;
    if (idx + 3 < n) rowptr[rb + idx + 3] = e + v0 + v1 + v2;
    carry += tot;
    __syncthreads();
  }
  if (tid == 0) rowptr[rb + n] = carry;
}

__global__ __launch_bounds__(256) void bcur_init(const int* __restrict__ rp,
                                                 int* __restrict__ bcur, CsrArgs a)
{
  int slot = blockIdx.x;
  for (int b = threadIdx.x; b < a.nb[slot]; b += 256)
    bcur[a.bkoff[slot] + b] = rp[a.rpoff[slot] + (b << 7)];
}

// pass B: per-block LDS bucketing + coalesced burst append into TMP
__global__ __launch_bounds__(256) void bucket_scatter(const int* __restrict__ e0,
                                                      const int* __restrict__ e1,
                                                      int* __restrict__ bcur,
                                                      u32* __restrict__ tmp, CsrArgs a)
{
  const int slot = blockIdx.x / 25;
  const int ch = blockIdx.x % 25;
  const int base = ch * 4096;
  const int n = (E_EDGES - base < 4096) ? (E_EDGES - base) : 4096;
  const int* E = a.lay[slot] ? e1 : e0;
  const int r = a.relid[slot];
  const int nb = a.nb[slot];
  const int tid = threadIdx.x;
  __shared__ int hist[256], start[256], gbase[256], lcur[256];
  __shared__ u32 sorted[4096];
  hist[tid] = 0;
  __syncthreads();
  const int* darr = E + (r * 2 + 1) * E_EDGES + base;
  const int* sarr = E + r * 2 * E_EDGES + base;
  for (int i = tid; i < n; i += 256) atomicAdd(&hist[darr[i] >> 7], 1);
  __syncthreads();
  if (tid == 0) {
    int s = 0;
    for (int b = 0; b < nb; b++) { start[b] = s; s += hist[b]; }
  }
  __syncthreads();
  if (tid < nb) {
    gbase[tid] = atomicAdd(&bcur[a.bkoff[slot] + tid], hist[tid]);
    lcur[tid] = start[tid];
  }
  __syncthreads();
  for (int i = tid; i < n; i += 256) {
    int dst = darr[i], src = sarr[i];
    int pos = atomicAdd(&lcur[dst >> 7], 1);
    sorted[pos] = ((u32)dst << 16) | (u32)src;
  }
  __syncthreads();
  u32* out = tmp + (long)slot * E_EDGES;
  for (int i = tid; i < n; i += 256) {
    u32 p = sorted[i];
    int b = p >> 23;
    out[gbase[b] + (i - start[b])] = p;
  }
}

// pass C: per-(slot,bucket) LDS counting-sort into exact CSR order, coalesced out
__global__ __launch_bounds__(256) void bucket_to_csr(const u32* __restrict__ tmp,
                                                     const int* __restrict__ rp,
                                                     int* __restrict__ esrc, CsrArgs a)
{
  const int b = blockIdx.x, slot = blockIdx.y;
  if (b >= a.nb[slot]) return;
  const int rb = a.rpoff[slot];
  const int rowlo = b << 7;
  int rowhi = rowlo + 128; if (rowhi > a.nd[slot]) rowhi = a.nd[slot];
  const int start = rp[rb + rowlo];
  const int end = rp[rb + rowhi];
  const int cnt = end - start;
  const int tid = threadIdx.x;
  __shared__ int scur[129];
  __shared__ u32 sbuf[8192];
  if (tid <= rowhi - rowlo) scur[tid] = rp[rb + rowlo + tid] - start;
  __syncthreads();
  const u32* in = tmp + (long)slot * E_EDGES + start;
  int* out = esrc + (long)slot * E_EDGES + start;
  if (cnt <= 8192) {
    for (int i = tid; i < cnt; i += 256) {
      u32 p = in[i];
      int d = (int)(p >> 16) - rowlo;
      int pos = atomicAdd(&scur[d], 1);
      sbuf[pos] = p & 0xFFFFu;
    }
    __syncthreads();
    for (int i = tid; i < cnt; i += 256) out[i] = (int)sbuf[i];
  } else {
    for (int i = tid; i < cnt; i += 256) {
      u32 p = in[i];
      int d = (int)(p >> 16) - rowlo;
      int pos = atomicAdd(&scur[d], 1);
      out[pos] = (int)(p & 0xFFFFu);
    }
  }
}

// ---------------- weight prep ----------------
__global__ __launch_bounds__(256) void wtstack_kernel(const float* __restrict__ wl,
                                                      const float* __restrict__ wr,
                                                      const float* __restrict__ bl,
                                                      u16* __restrict__ WTG,
                                                      float* __restrict__ BLS, WTStackArgs a)
{
  int slot = blockIdx.y;
  int t = blockIdx.x * 256 + threadIdx.x;
  int krel = t & 127, n = t >> 7;
  int sr = a.srcrel[slot];
  float v;
  if (sr >= 0) {
    v = wl[(long)sr * 16384 + krel * 128 + n];
  } else {
    int g = a.grp[slot];
    v = 0.f;
    for (int i = 0; i < a.gnr[g]; i++) v += wr[(long)a.grel[g][i] * 16384 + krel * 128 + n];
    if (t < 128) {
      float b = 0.f;
      for (int i = 0; i < a.gnr[g]; i++) b += bl[a.grel[g][i] * 128 + t];
      BLS[g * 128 + t] = b;
    }
  }
  WTG[a.outoff[slot] + (long)n * a.pitch[slot] + a.koff[slot] + krel] = f2bf(v);
}

__global__ __launch_bounds__(256) void wt_kernel(WTArgs a)
{
  int s = blockIdx.y;
  int idx = blockIdx.x * 256 + threadIdx.x;
  int K = a.K[s], N = a.N[s], Kpad = a.Kpad[s];
  if (idx >= N * Kpad) return;
  int n = idx / Kpad, k = idx - n * Kpad;
  a.out[s][idx] = (k < K) ? f2bf(a.W[s][(long)k * N + n]) : (u16)0;
}

__global__ __launch_bounds__(256) void f2b_kernel(F2BArgs a)
{
  int s = blockIdx.y;
  int i = blockIdx.x * 256 + threadIdx.x;
  if (i >= a.n4[s]) return;
  float4 v = ((const float4*)a.s[s])[i];
  ushort4 o; o.x = f2bf(v.x); o.y = f2bf(v.y); o.z = f2bf(v.z); o.w = f2bf(v.w);
  ((ushort4*)a.d[s])[i] = o;
}

// cross-layer permutation: pos[g][p] = index j in map1 with map1[j]==map0[p], else -1
__global__ __launch_bounds__(256) void pos_kernel(PosArgs a)
{
  int g = blockIdx.y;
  int i = blockIdx.x * 256 + threadIdx.x;
  if (i >= a.n[g]) return;
  int key = a.m0[g][i];
  const int* m1 = a.m1[g];
  int lo = 0, hi = a.n[g] - 1, pos = -1;
  while (lo <= hi) {
    int mid = (lo + hi) >> 1;
    int v = m1[mid];
    if (v == key) { pos = mid; break; }
    if (v < key) lo = mid + 1; else hi = mid - 1;
  }
  a.pos[g][i] = pos;
}

// ---------------- aggregation ----------------
__global__ __launch_bounds__(256) void agg_kernel(AggArgs a)
{
  int slot = blockIdx.y;
  int wave = threadIdx.x >> 6, lane = threadIdx.x & 63;
  int row = blockIdx.x * 4 + wave;
  if (row >= a.nd) return;
  u16* dst = a.abuf + (long)row * a.pitch + slot * 128 + lane * 2;
  const u32* x2 = (const u32*)a.xsrc[slot];
  if (slot == a.nrels) {
    *(u32*)dst = x2[(long)row * 64 + lane];
    return;
  }
  const int* rp = a.rowptr[slot];
  int c0 = rp[row], c1 = rp[row + 1];
  const int* es = a.esrc[slot];
  float ax = 0.f, ay = 0.f;
  int e = c0;
  for (; e + 4 <= c1; e += 4) {
    int s0 = es[e], s1 = es[e + 1], s2 = es[e + 2], s3 = es[e + 3];
    u32 v0 = x2[(long)s0 * 64 + lane];
    u32 v1 = x2[(long)s1 * 64 + lane];
    u32 v2 = x2[(long)s2 * 64 + lane];
    u32 v3 = x2[(long)s3 * 64 + lane];
    ax += bf2f(v0 & 0xFFFF) + bf2f(v1 & 0xFFFF) + bf2f(v2 & 0xFFFF) + bf2f(v3 & 0xFFFF);
    ay += bf2f(v0 >> 16) + bf2f(v1 >> 16) + bf2f(v2 >> 16) + bf2f(v3 >> 16);
  }
  for (; e < c1; e++) {
    u32 v = x2[(long)es[e] * 64 + lane];
    ax += bf2f(v & 0xFFFF);
    ay += bf2f(v >> 16);
  }
  int c = c1 - c0;
  float inv = 1.f / (float)(c > 1 ? c : 1);
  ax *= inv; ay *= inv;
  *(u32*)dst = (u32)f2bf(ax) | ((u32)f2bf(ay) << 16);
}

// ---------------- batched head reduce ----------------
__global__ __launch_bounds__(64) void head_reduce2(HeadRArgs a)
{
  int row = blockIdx.x;
  int z = blockIdx.y;
  int lane = threadIdx.x;
  const float* h = a.hid[z] + (long)row * 256;
  const float* w2 = a.w2[z];
  float s = h[lane] * w2[lane] + h[lane + 64] * w2[lane + 64]
          + h[lane + 128] * w2[lane + 128] + h[lane + 192] * w2[lane + 192];
  #pragma unroll
  for (int off = 32; off >= 1; off >>= 1) s += __shfl_down(s, off, 64);
  if (lane == 0) {
    float v = s + a.b2[z][0];
    if (z == 0) v = 1.0f / (1.0f + expf(-v));
    a.out[row * 2 + z] = v;
  }
}

// ---------------- host orchestration ----------------
extern "C" void kernel_launch(void* const* d_in, const int* in_sizes, int n_in,
                              void* d_out, int out_size, void* d_ws, size_t ws_size,
                              hipStream_t stream)
{
  static const int NT[6] = {25000, 15000, 4000, 12000, 12000, 15000};
  static const int REL_S[19] = {2,0,2,1,0,1,3,3,1,3,1,3,4,5,0,5,1,0,1};
  static const int REL_D[19] = {0,2,1,2,1,0,3,1,3,1,3,4,3,0,5,1,5,1,0};

  auto xin   = [&](int t, int L) { return (const float*)d_in[L * 13 + 2 * t]; };
  auto mapin = [&](int t, int L) { return (const int*)d_in[L * 13 + 2 * t + 1]; };
  const int* edges0 = (const int*)d_in[12];
  const int* edges1 = (const int*)d_in[25];
  const float* W_in_atac  = (const float*)d_in[26];
  const float* b_in_atac  = (const float*)d_in[27];
  const float* W_in_gene  = (const float*)d_in[28];
  const float* b_in_gene  = (const float*)d_in[29];
  const float* W_in_pname = (const float*)d_in[30];
  const float* b_in_pname = (const float*)d_in[31];
  const float* conv_wl = (const float*)d_in[32];
  const float* conv_bl = (const float*)d_in[33];
  const float* conv_wr = (const float*)d_in[34];
  const float* mlp_w1 = (const float*)d_in[35];
  const float* mlp_b1 = (const float*)d_in[36];
  const float* mlp_w2 = (const float*)d_in[37];
  const float* mlp_b2 = (const float*)d_in[38];
  const float* gd_w1 = (const float*)d_in[39];
  const float* gd_b1 = (const float*)d_in[40];
  const float* gd_w2 = (const float*)d_in[41];
  const float* gd_b2 = (const float*)d_in[42];
  const float* gv_w1 = (const float*)d_in[43];
  const float* gv_b1 = (const float*)d_in[44];
  const float* gv_w2 = (const float*)d_in[45];
  const float* gv_b2 = (const float*)d_in[46];
  float* out = (float*)d_out;

  // ---- workspace carve (~113 MB): fp32, bf16, int sections ----
  float* fp = (float*)d_ws;
  auto takef = [&](size_t n) { float* q = fp; fp += n; return q; };
  float* BLS  = takef(5 * 128);
  float* G1   = takef((size_t)15000 * 128);
  u16* bp = (u16*)fp;
  auto takeb = [&](size_t n) { u16* q = bp; bp += n; return q; };
  u16* XB0[6]; u16* XB1[6];
  XB0[0] = takeb((size_t)25000 * 128);
  XB0[1] = takeb((size_t)15000 * 128);
  XB0[2] = takeb((size_t)4000 * 128);
  XB0[3] = takeb((size_t)12000 * 128);
  XB0[4] = takeb((size_t)12000 * 128);
  XB0[5] = takeb((size_t)15000 * 128);
  XB1[0] = takeb((size_t)25000 * 128);
  XB1[1] = takeb((size_t)15000 * 128);
  XB1[2] = takeb((size_t)4000 * 128);
  XB1[3] = takeb((size_t)12000 * 128);
  XB1[4] = nullptr;
  XB1[5] = takeb((size_t)15000 * 128);
  u16* ABUF = takeb((size_t)16000000);       // >= 25000*640 and 15000*896
  u16* NWB  = takeb((size_t)25000 * 128);
  u16* HIDB = takeb((size_t)25000 * 256);
  u16* WTG  = takeb(376832);
  u16* WTIA = takeb(128 * 288);
  u16* WTIG = takeb(128 * 160);
  u16* WTIP = takeb(128 * 160);
  u16* WTM1 = takeb((size_t)5 * 32768);
  u16* WTM2 = takeb((size_t)5 * 32768);
  u16* WTHD = takeb(32768);
  u16* WTHV = takeb(32768);
  uintptr_t ipa = ((uintptr_t)bp + 15) & ~(uintptr_t)15;
  int* ip = (int*)ipa;
  auto takei = [&](size_t n) { int* q = ip; ip += n; return q; };
  int* CNT  = takei(366000);
  int* RP   = takei(366024);
  int* BCUR = takei(4704);
  int* POSB = takei(71000);
  int* ESRC = takei((size_t)24 * E_EDGES);
  // aliases (disjoint lifetimes): TMP in CSR build (step 3); head hiddens in step 7
  u32* TMP = (u32*)ABUF;
  float* HIDF0 = (float*)ABUF;
  float* HIDF1 = (float*)(ABUF + (size_t)15000 * 256 * 2);

  // dst-type groups
  static const int GD[5]       = {0, 1, 2, 3, 5};
  static const int GNR[5]      = {4, 6, 2, 4, 2};
  static const int GRELS[5][6] = {{0,5,13,18,0,0},{2,4,7,9,15,17},{1,3,0,0,0,0},
                                  {6,8,10,12,0,0},{14,16,0,0,0,0}};
  static const int GPITCH[5]   = {640, 896, 384, 640, 384};
  long gbaseT[5];
  {
    long o = 0;
    for (int g = 0; g < 5; g++) { gbaseT[g] = o; o += (long)128 * GPITCH[g]; }
  }
  int* POSg[5];
  {
    int o = 0;
    for (int g = 0; g < 5; g++) { POSg[g] = POSB + o; o += NT[GD[g]]; }
  }

  // 1) weight prep + POS permutation
  {
    WTStackArgs wa{};
    int j = 0;
    for (int g = 0; g < 5; g++) {
      wa.gnr[g] = GNR[g];
      for (int i = 0; i < 6; i++) wa.grel[g][i] = GRELS[g][i];
      for (int s = 0; s <= GNR[g]; s++, j++) {
        wa.srcrel[j] = (s < GNR[g]) ? GRELS[g][s] : -1;
        wa.grp[j] = g;
        wa.outoff[j] = gbaseT[g];
        wa.koff[j] = s * 128;
        wa.pitch[j] = GPITCH[g];
      }
    }
    hipLaunchKernelGGL(wtstack_kernel, dim3(64, 23), dim3(256), 0, stream,
                       conv_wl, conv_wr, conv_bl, WTG, BLS, wa);
  }
  {
    WTArgs pa{};
    int s = 0;
    auto add = [&](const float* W, u16* o, int K, int N, int Kpad) {
      pa.W[s] = W; pa.out[s] = o; pa.K[s] = K; pa.N[s] = N; pa.Kpad[s] = Kpad; s++;
    };
    add(W_in_atac,  WTIA, 257, 128, 288);
    add(W_in_gene,  WTIG, 129, 128, 160);
    add(W_in_pname, WTIP, 129, 128, 160);
    for (int g = 0; g < 5; g++) {
      int d = GD[g];
      add(mlp_w1 + (long)d * 128 * 256, WTM1 + (long)g * 32768, 128, 256, 128);
      add(mlp_w2 + (long)d * 256 * 128, WTM2 + (long)g * 32768, 256, 128, 256);
    }
    add(gd_w1, WTHD, 128, 256, 128);
    add(gv_w1, WTHV, 128, 256, 128);
    hipLaunchKernelGGL(wt_kernel, dim3(144, 15), dim3(256), 0, stream, pa);
  }
  {
    PosArgs pa{};
    for (int g = 0; g < 5; g++) {
      int d = GD[g];
      pa.m0[g] = mapin(d, 0); pa.m1[g] = mapin(d, 1); pa.pos[g] = POSg[g]; pa.n[g] = NT[d];
    }
    hipLaunchKernelGGL(pos_kernel, dim3(98, 5), dim3(256), 0, stream, pa);
  }

  auto mg = [&](int af32, int of32, int relu, const void* A, const u16* WT,
                const float* b, void* C, int M, int K, int Kpad, int N) {
    dim3 grid((M + 63) / 64, N / 128);
    if (af32) {
      hipLaunchKernelGGL(HIP_KERNEL_NAME(tgemm<1,0,0>), grid, dim3(256), 0, stream, A, WT, b, C, M, K, Kpad, N);
    } else {
      if (of32)      hipLaunchKernelGGL(HIP_KERNEL_NAME(tgemm<0,1,0>), grid, dim3(256), 0, stream, A, WT, b, C, M, K, Kpad, N);
      else if (relu) hipLaunchKernelGGL(HIP_KERNEL_NAME(tgemm<0,0,1>), grid, dim3(256), 0, stream, A, WT, b, C, M, K, Kpad, N);
      else           hipLaunchKernelGGL(HIP_KERNEL_NAME(tgemm<0,0,0>), grid, dim3(256), 0, stream, A, WT, b, C, M, K, Kpad, N);
    }
  };

  // 2) input linears (batched) + raw-table converts (batched)
  {
    InLinArgs ia{};
    auto add = [&](int s, const float* A, const u16* WT, const float* b, u16* C,
                   int M, int K, int Kpad) {
      ia.A[s] = A; ia.WT[s] = WT; ia.bias[s] = b; ia.C[s] = C;
      ia.M[s] = M; ia.K[s] = K; ia.Kpad[s] = Kpad;
    };
    add(0, xin(0,0), WTIA, b_in_atac,  XB0[0], 25000, 257, 288);
    add(1, xin(1,0), WTIG, b_in_gene,  XB0[1], 15000, 129, 160);
    add(2, xin(4,0), WTIP, b_in_pname, XB0[4], 12000, 129, 160);
    add(3, xin(0,1), WTIA, b_in_atac,  XB1[0], 25000, 257, 288);
    add(4, xin(1,1), WTIG, b_in_gene,  XB1[1], 15000, 129, 160);
    hipLaunchKernelGGL(tgemm_in, dim3(391, 1, 5), dim3(256), 0, stream, ia);
  }
  {
    F2BArgs fa{};
    const float* ss[6] = {xin(2,0), xin(3,0), xin(5,0), xin(2,1), xin(3,1), xin(5,1)};
    u16* dd[6] = {XB0[2], XB0[3], XB0[5], XB1[2], XB1[3], XB1[5]};
    int nn[6] = {4000*32, 12000*32, 15000*32, 4000*32, 12000*32, 15000*32};
    for (int s = 0; s < 6; s++) { fa.s[s] = ss[s]; fa.d[s] = dd[s]; fa.n4[s] = nn[s]; }
    hipLaunchKernelGGL(f2b_kernel, dim3(1875, 6), dim3(256), 0, stream, fa);
  }

  // 3) CSR build (combined L0 18 + L1 6 slots): hist -> scan -> bucket passes
  static const int L0R[18] = {0,1,2,3,4,5,6,7,8,9,10,12,13,14,15,16,17,18};
  static const int L1R[6]  = {2, 4, 7, 9, 15, 17};
  int rpoffByRel[19], slotByRel[19], rpoff1[19], slot1[19];
  CsrArgs cc{};
  {
    int co = 0, ro = 0, bo = 0, s = 0;
    for (int i = 0; i < 18; i++, s++) {
      int r = L0R[i];
      cc.relid[s] = r; cc.lay[s] = 0; int nd = NT[REL_D[r]];
      cc.nd[s] = nd; cc.cntoff[s] = co; cc.rpoff[s] = ro;
      cc.bkoff[s] = bo; cc.nb[s] = (nd + 127) >> 7;
      rpoffByRel[r] = ro; slotByRel[r] = s;
      co += nd; ro += nd + 1; bo += cc.nb[s];
    }
    for (int i = 0; i < 6; i++, s++) {
      int r = L1R[i];
      cc.relid[s] = r; cc.lay[s] = 1;
      cc.nd[s] = 15000; cc.cntoff[s] = co; cc.rpoff[s] = ro;
      cc.bkoff[s] = bo; cc.nb[s] = (15000 + 127) >> 7;
      rpoff1[r] = ro; slot1[r] = s;
      co += 15000; ro += 15001; bo += cc.nb[s];
    }
    hipMemsetAsync(CNT, 0, (size_t)co * 4, stream);
    hipLaunchKernelGGL(hist_kernel, dim3(24 * 391), dim3(256), 0, stream, edges0, edges1, CNT, cc);
    hipLaunchKernelGGL(scan_kernel, dim3(24), dim3(256), 0, stream, CNT, RP, cc);
    hipLaunchKernelGGL(bcur_init, dim3(24), dim3(256), 0, stream, RP, BCUR, cc);
    hipLaunchKernelGGL(bucket_scatter, dim3(24 * 25), dim3(256), 0, stream,
                       edges0, edges1, BCUR, TMP, cc);
    hipLaunchKernelGGL(bucket_to_csr, dim3(196, 24), dim3(256), 0, stream, TMP, RP, ESRC, cc);
  }

  // 4) per dst group: aggregate -> conv GEMM -> MLP1 -> MLP2+scatter
  for (int g = 0; g < 5; g++) {
    int d = GD[g];
    AggArgs aa{};
    aa.nrels = GNR[g]; aa.nd = NT[d]; aa.pitch = GPITCH[g]; aa.abuf = ABUF;
    for (int i = 0; i < GNR[g]; i++) {
      int r = GRELS[g][i];
      aa.xsrc[i]   = XB0[REL_S[r]];
      aa.rowptr[i] = RP + rpoffByRel[r];
      aa.esrc[i]   = ESRC + (long)slotByRel[r] * E_EDGES;
    }
    aa.xsrc[GNR[g]] = XB0[d];
    hipLaunchKernelGGL(agg_kernel, dim3((NT[d] + 3) / 4, GNR[g] + 1), dim3(256), 0, stream, aa);
    mg(0,0,0, ABUF, WTG + gbaseT[g], BLS + g * 128, NWB, NT[d], GPITCH[g], GPITCH[g], 128);
    mg(0,0,1, NWB,  WTM1 + (long)g * 32768, mlp_b1 + d * 256, HIDB, NT[d], 128, 128, 256);
    hipLaunchKernelGGL(tgemm_scat, dim3((NT[d] + 63) / 64), dim3(256), 0, stream,
                       HIDB, WTM2 + (long)g * 32768, mlp_b2 + d * 128, POSg[g],
                       XB1[d], NT[d], 256);
  }

  // 5) layer-1 gene conv: aggregate + GEMM -> G1 (fp32)
  {
    AggArgs aa{};
    aa.nrels = 6; aa.nd = 15000; aa.pitch = 896; aa.abuf = ABUF;
    for (int i = 0; i < 6; i++) {
      int r = L1R[i];
      aa.xsrc[i]   = XB1[REL_S[r]];
      aa.rowptr[i] = RP + rpoff1[r];
      aa.esrc[i]   = ESRC + (long)slot1[r] * E_EDGES;
    }
    aa.xsrc[6] = XB1[1];
    hipLaunchKernelGGL(agg_kernel, dim3((15000 + 3) / 4, 7), dim3(256), 0, stream, aa);
    mg(0,1,0, ABUF, WTG + gbaseT[1], BLS + 1 * 128, G1, 15000, 896, 896, 128);
  }

  // 6) gene heads: batched MFMA (z=2) + batched reduce (HIDF* alias ABUF, now free)
  {
    HeadArgs ha{};
    ha.WT[0] = WTHD; ha.WT[1] = WTHV;
    ha.b1[0] = gd_b1; ha.b1[1] = gv_b1;
    ha.hid[0] = HIDF0; ha.hid[1] = HIDF1;
    ha.A = G1; ha.M = 15000;
    hipLaunchKernelGGL(tgemm_head, dim3(235, 2, 2), dim3(256), 0, stream, ha);
    HeadRArgs hr{};
    hr.hid[0] = HIDF0; hr.hid[1] = HIDF1;
    hr.w2[0] = gd_w2; hr.w2[1] = gv_w2;
    hr.b2[0] = gd_b2; hr.b2[1] = gv_b2;
    hr.out = out;
    hipLaunchKernelGGL(head_reduce2, dim3(15000, 2), dim3(64), 0, stream, hr);
  }
}

// Round 9
// 764.088 us; speedup vs baseline: 6.0160x; 1.1293x over previous
//
#include <hip/hip_runtime.h>
#include <math.h>

#define E_EDGES 100000

typedef unsigned short u16;
typedef unsigned int u32;

using bfrag = __attribute__((ext_vector_type(8))) short;
using ffrag = __attribute__((ext_vector_type(4))) float;

__device__ inline float bf2f(u32 u) { union { u32 i; float f; } c; c.i = u << 16; return c.f; }
__device__ inline u16 f2bf(float f) {
  union { u32 i; float f; } c; c.f = f;
  u32 u = c.i;
  return (u16)((u + 0x7FFFu + ((u >> 16) & 1u)) >> 16);
}

// ---------------- structs ----------------
struct CsrArgs { int relid[24]; int lay[24]; int nd[24]; int rpoff[24];
                 int bkoff[24]; int bboff[24]; int nb[24]; };

struct AggArgs {
  const u16* xsrc[7];
  const int* rowptr[6];
  const int* esrc[6];
  u16* abuf;
  int nrels, nd, pitch;
};

struct WTStackArgs {
  int srcrel[23]; int grp[23]; long outoff[23]; int koff[23]; int pitch[23];
  int gnr[5]; int grel[5][6];
};

struct WTArgs { const float* W[15]; u16* out[15]; int K[15]; int N[15]; int Kpad[15]; };
struct F2BArgs { const float* s[6]; u16* d[6]; int n4[6]; };
struct InLinArgs { const float* A[5]; const u16* WT[5]; const float* bias[5]; u16* C[5];
                   int M[5]; int K[5]; int Kpad[5]; };
struct PosArgs { const int* m0[5]; const int* m1[5]; int* pos[5]; int n[5]; };
struct HeadArgs { const u16* WT[2]; const float* b1[2]; float* hid[2]; const float* A; int M; };
struct HeadRArgs { const float* hid[2]; const float* w2[2]; const float* b2[2]; float* out; };

// ---------------- MFMA GEMM (verified R6 structure) ----------------
template <int AF32, int OF32, int RELU>
__global__ __launch_bounds__(256) void tgemm(const void* __restrict__ Av,
                                             const u16* __restrict__ WT,
                                             const float* __restrict__ bias,
                                             void* __restrict__ Cv,
                                             int M, int K, int Kpad, int N)
{
  __shared__ u16 sA[64 * 40];
  __shared__ u16 sB[128 * 40];
  const int tid = threadIdx.x;
  const int w = tid >> 6, lane = tid & 63;
  const int quad = lane >> 4, m = lane & 15;
  const int rowbase = blockIdx.x * 64;
  const int colbase = blockIdx.y * 128;
  const int sr = tid >> 2, sc = tid & 3;
  const int br = tid >> 1, bh = tid & 1;
  ffrag acc[8];
  #pragma unroll
  for (int i = 0; i < 8; i++) { acc[i][0] = 0.f; acc[i][1] = 0.f; acc[i][2] = 0.f; acc[i][3] = 0.f; }

  for (int kt = 0; kt < Kpad / 32; kt++) {
    int gr = rowbase + sr, gk = kt * 32 + sc * 8;
    uint4 st = make_uint4(0, 0, 0, 0);
    if (AF32) {
      const float* A = (const float*)Av;
      if (gr < M) {
        const float* row = A + (long)gr * K + gk;
        float v[8];
        #pragma unroll
        for (int i = 0; i < 8; i++) v[i] = (gk + i < K) ? row[i] : 0.f;
        st.x = (u32)f2bf(v[0]) | ((u32)f2bf(v[1]) << 16);
        st.y = (u32)f2bf(v[2]) | ((u32)f2bf(v[3]) << 16);
        st.z = (u32)f2bf(v[4]) | ((u32)f2bf(v[5]) << 16);
        st.w = (u32)f2bf(v[6]) | ((u32)f2bf(v[7]) << 16);
      }
    } else {
      const u16* A = (const u16*)Av;
      if (gr < M) st = *(const uint4*)(A + (long)gr * K + gk);
    }
    const u16* wrow = WT + (long)(colbase + br) * Kpad + kt * 32 + bh * 16;
    uint4 b0 = *(const uint4*)wrow;
    uint4 b1 = *(const uint4*)(wrow + 8);

    if (kt) __syncthreads();
    *(uint4*)&sA[sr * 40 + sc * 8] = st;
    *(uint4*)&sB[br * 40 + bh * 16] = b0;
    *(uint4*)&sB[br * 40 + bh * 16 + 8] = b1;
    __syncthreads();

    bfrag a = *(const bfrag*)&sA[(w * 16 + m) * 40 + quad * 8];
    #pragma unroll
    for (int ct = 0; ct < 8; ct++) {
      bfrag b = *(const bfrag*)&sB[(ct * 16 + m) * 40 + quad * 8];
      acc[ct] = __builtin_amdgcn_mfma_f32_16x16x32_bf16(a, b, acc[ct], 0, 0, 0);
    }
  }

  #pragma unroll
  for (int ct = 0; ct < 8; ct++) {
    int col = colbase + ct * 16 + m;
    float bv = bias ? bias[col] : 0.f;
    #pragma unroll
    for (int r = 0; r < 4; r++) {
      int row = rowbase + w * 16 + quad * 4 + r;
      if (row < M) {
        float v = acc[ct][r] + bv;
        if (RELU) v = fmaxf(v, 0.f);
        long off = (long)row * N + col;
        if (OF32) ((float*)Cv)[off] = v;
        else ((u16*)Cv)[off] = f2bf(v);
      }
    }
  }
}

// ---------------- mlp2 GEMM with fused row-permute scatter (bf16 A, bf16 out) --------
__global__ __launch_bounds__(256) void tgemm_scat(const u16* __restrict__ A,
                                                  const u16* __restrict__ WT,
                                                  const float* __restrict__ bias,
                                                  const int* __restrict__ POS,
                                                  u16* __restrict__ C,
                                                  int M, int Kpad)
{
  __shared__ u16 sA[64 * 40];
  __shared__ u16 sB[128 * 40];
  const int tid = threadIdx.x;
  const int w = tid >> 6, lane = tid & 63;
  const int quad = lane >> 4, m = lane & 15;
  const int rowbase = blockIdx.x * 64;
  const int sr = tid >> 2, sc = tid & 3;
  const int br = tid >> 1, bh = tid & 1;
  ffrag acc[8];
  #pragma unroll
  for (int i = 0; i < 8; i++) { acc[i][0] = 0.f; acc[i][1] = 0.f; acc[i][2] = 0.f; acc[i][3] = 0.f; }

  for (int kt = 0; kt < Kpad / 32; kt++) {
    int gr = rowbase + sr, gk = kt * 32 + sc * 8;
    uint4 st = make_uint4(0, 0, 0, 0);
    if (gr < M) st = *(const uint4*)(A + (long)gr * Kpad + gk);
    const u16* wrow = WT + (long)br * Kpad + kt * 32 + bh * 16;
    uint4 b0 = *(const uint4*)wrow;
    uint4 b1 = *(const uint4*)(wrow + 8);

    if (kt) __syncthreads();
    *(uint4*)&sA[sr * 40 + sc * 8] = st;
    *(uint4*)&sB[br * 40 + bh * 16] = b0;
    *(uint4*)&sB[br * 40 + bh * 16 + 8] = b1;
    __syncthreads();

    bfrag a = *(const bfrag*)&sA[(w * 16 + m) * 40 + quad * 8];
    #pragma unroll
    for (int ct = 0; ct < 8; ct++) {
      bfrag b = *(const bfrag*)&sB[(ct * 16 + m) * 40 + quad * 8];
      acc[ct] = __builtin_amdgcn_mfma_f32_16x16x32_bf16(a, b, acc[ct], 0, 0, 0);
    }
  }

  #pragma unroll
  for (int ct = 0; ct < 8; ct++) {
    int col = ct * 16 + m;
    float bv = bias[col];
    #pragma unroll
    for (int r = 0; r < 4; r++) {
      int row = rowbase + w * 16 + quad * 4 + r;
      if (row < M) {
        int j = POS[row];
        if (j >= 0) C[(long)j * 128 + col] = f2bf(acc[ct][r] + bv);
      }
    }
  }
}

// ---------------- batched input linears ----------------
__global__ __launch_bounds__(256) void tgemm_in(InLinArgs a)
{
  const int z = blockIdx.z;
  const int M = a.M[z], K = a.K[z], Kpad = a.Kpad[z];
  const int rowbase = blockIdx.x * 64;
  if (rowbase >= M) return;
  __shared__ u16 sA[64 * 40];
  __shared__ u16 sB[128 * 40];
  const int tid = threadIdx.x;
  const int w = tid >> 6, lane = tid & 63;
  const int quad = lane >> 4, m = lane & 15;
  const int sr = tid >> 2, sc = tid & 3;
  const int br = tid >> 1, bh = tid & 1;
  const float* A = a.A[z];
  const u16* WT = a.WT[z];
  ffrag acc[8];
  #pragma unroll
  for (int i = 0; i < 8; i++) { acc[i][0] = 0.f; acc[i][1] = 0.f; acc[i][2] = 0.f; acc[i][3] = 0.f; }

  for (int kt = 0; kt < Kpad / 32; kt++) {
    int gr = rowbase + sr, gk = kt * 32 + sc * 8;
    uint4 st = make_uint4(0, 0, 0, 0);
    if (gr < M) {
      const float* row = A + (long)gr * K + gk;
      float v[8];
      #pragma unroll
      for (int i = 0; i < 8; i++) v[i] = (gk + i < K) ? row[i] : 0.f;
      st.x = (u32)f2bf(v[0]) | ((u32)f2bf(v[1]) << 16);
      st.y = (u32)f2bf(v[2]) | ((u32)f2bf(v[3]) << 16);
      st.z = (u32)f2bf(v[4]) | ((u32)f2bf(v[5]) << 16);
      st.w = (u32)f2bf(v[6]) | ((u32)f2bf(v[7]) << 16);
    }
    const u16* wrow = WT + (long)br * Kpad + kt * 32 + bh * 16;
    uint4 b0 = *(const uint4*)wrow;
    uint4 b1 = *(const uint4*)(wrow + 8);

    if (kt) __syncthreads();
    *(uint4*)&sA[sr * 40 + sc * 8] = st;
    *(uint4*)&sB[br * 40 + bh * 16] = b0;
    *(uint4*)&sB[br * 40 + bh * 16 + 8] = b1;
    __syncthreads();

    bfrag av = *(const bfrag*)&sA[(w * 16 + m) * 40 + quad * 8];
    #pragma unroll
    for (int ct = 0; ct < 8; ct++) {
      bfrag bv = *(const bfrag*)&sB[(ct * 16 + m) * 40 + quad * 8];
      acc[ct] = __builtin_amdgcn_mfma_f32_16x16x32_bf16(av, bv, acc[ct], 0, 0, 0);
    }
  }

  const float* bias = a.bias[z];
  u16* C = a.C[z];
  #pragma unroll
  for (int ct = 0; ct < 8; ct++) {
    int col = ct * 16 + m;
    float bv = bias[col];
    #pragma unroll
    for (int r = 0; r < 4; r++) {
      int row = rowbase + w * 16 + quad * 4 + r;
      if (row < M) C[(long)row * 128 + col] = f2bf(acc[ct][r] + bv);
    }
  }
}

// ---------------- batched gene heads (fp32 A, fp32 out, relu, N=256) ----------------
__global__ __launch_bounds__(256) void tgemm_head(HeadArgs a)
{
  const int z = blockIdx.z;
  const int M = a.M;
  const int rowbase = blockIdx.x * 64;
  const int colbase = blockIdx.y * 128;
  __shared__ u16 sA[64 * 40];
  __shared__ u16 sB[128 * 40];
  const int tid = threadIdx.x;
  const int w = tid >> 6, lane = tid & 63;
  const int quad = lane >> 4, m = lane & 15;
  const int sr = tid >> 2, sc = tid & 3;
  const int br = tid >> 1, bh = tid & 1;
  const float* A = a.A;
  const u16* WT = a.WT[z];
  ffrag acc[8];
  #pragma unroll
  for (int i = 0; i < 8; i++) { acc[i][0] = 0.f; acc[i][1] = 0.f; acc[i][2] = 0.f; acc[i][3] = 0.f; }

  for (int kt = 0; kt < 4; kt++) {
    int gr = rowbase + sr, gk = kt * 32 + sc * 8;
    uint4 st = make_uint4(0, 0, 0, 0);
    if (gr < M) {
      const float* row = A + (long)gr * 128 + gk;
      float v[8];
      #pragma unroll
      for (int i = 0; i < 8; i++) v[i] = row[i];
      st.x = (u32)f2bf(v[0]) | ((u32)f2bf(v[1]) << 16);
      st.y = (u32)f2bf(v[2]) | ((u32)f2bf(v[3]) << 16);
      st.z = (u32)f2bf(v[4]) | ((u32)f2bf(v[5]) << 16);
      st.w = (u32)f2bf(v[6]) | ((u32)f2bf(v[7]) << 16);
    }
    const u16* wrow = WT + (long)(colbase + br) * 128 + kt * 32 + bh * 16;
    uint4 b0 = *(const uint4*)wrow;
    uint4 b1 = *(const uint4*)(wrow + 8);

    if (kt) __syncthreads();
    *(uint4*)&sA[sr * 40 + sc * 8] = st;
    *(uint4*)&sB[br * 40 + bh * 16] = b0;
    *(uint4*)&sB[br * 40 + bh * 16 + 8] = b1;
    __syncthreads();

    bfrag av = *(const bfrag*)&sA[(w * 16 + m) * 40 + quad * 8];
    #pragma unroll
    for (int ct = 0; ct < 8; ct++) {
      bfrag bv = *(const bfrag*)&sB[(ct * 16 + m) * 40 + quad * 8];
      acc[ct] = __builtin_amdgcn_mfma_f32_16x16x32_bf16(av, bv, acc[ct], 0, 0, 0);
    }
  }

  const float* bias = a.b1[z];
  float* C = a.hid[z];
  #pragma unroll
  for (int ct = 0; ct < 8; ct++) {
    int col = colbase + ct * 16 + m;
    float bv = bias[col];
    #pragma unroll
    for (int r = 0; r < 4; r++) {
      int row = rowbase + w * 16 + quad * 4 + r;
      if (row < M) C[(long)row * 256 + col] = fmaxf(acc[ct][r] + bv, 0.f);
    }
  }
}

// ---------------- CSR build: bucket-level histogram (LDS-privatized) ----------------
__global__ __launch_bounds__(256) void bhist_kernel(const int* __restrict__ e0,
                                                    const int* __restrict__ e1,
                                                    int* __restrict__ bcnt, CsrArgs a)
{
  const int slot = blockIdx.x / 25;
  const int ch = blockIdx.x % 25;
  const int base = ch * 4096;
  const int n = (E_EDGES - base < 4096) ? (E_EDGES - base) : 4096;
  const int* E = a.lay[slot] ? e1 : e0;
  const int r = a.relid[slot];
  const int tid = threadIdx.x;
  __shared__ int h[256];
  h[tid] = 0;
  __syncthreads();
  const int* darr = E + (r * 2 + 1) * E_EDGES + base;
  for (int i = tid; i < n; i += 256) atomicAdd(&h[darr[i] >> 7], 1);
  __syncthreads();
  if (tid < a.nb[slot] && h[tid]) atomicAdd(&bcnt[a.bkoff[slot] + tid], h[tid]);
}

// per-slot scan of bucket counts -> bucket bases (exclusive, + sentinel) and cursors
__global__ __launch_bounds__(256) void bscan_kernel(const int* __restrict__ bcnt,
                                                    int* __restrict__ bbase,
                                                    int* __restrict__ bcur, CsrArgs a)
{
  int slot = blockIdx.x;
  int nb = a.nb[slot];
  int tid = threadIdx.x, lane = tid & 63, w = tid >> 6;
  __shared__ int ws[4];
  int v = (tid < nb) ? bcnt[a.bkoff[slot] + tid] : 0;
  int si = v;
  #pragma unroll
  for (int off = 1; off < 64; off <<= 1) {
    int t = __shfl_up(si, off, 64);
    if (lane >= off) si += t;
  }
  if (lane == 63) ws[w] = si;
  __syncthreads();
  int woff = 0;
  #pragma unroll
  for (int k = 0; k < 4; k++) if (k < w) woff += ws[k];
  int excl = woff + si - v;
  if (tid < nb) { bbase[a.bboff[slot] + tid] = excl; bcur[a.bkoff[slot] + tid] = excl; }
  if (tid == 0) bbase[a.bboff[slot] + nb] = ws[0] + ws[1] + ws[2] + ws[3];
}

// pass B: per-block LDS bucketing + coalesced burst append into TMP
__global__ __launch_bounds__(256) void bucket_scatter(const int* __restrict__ e0,
                                                      const int* __restrict__ e1,
                                                      int* __restrict__ bcur,
                                                      u32* __restrict__ tmp, CsrArgs a)
{
  const int slot = blockIdx.x / 25;
  const int ch = blockIdx.x % 25;
  const int base = ch * 4096;
  const int n = (E_EDGES - base < 4096) ? (E_EDGES - base) : 4096;
  const int* E = a.lay[slot] ? e1 : e0;
  const int r = a.relid[slot];
  const int nb = a.nb[slot];
  const int tid = threadIdx.x;
  __shared__ int hist[256], start[256], gbase[256], lcur[256];
  __shared__ u32 sorted[4096];
  hist[tid] = 0;
  __syncthreads();
  const int* darr = E + (r * 2 + 1) * E_EDGES + base;
  const int* sarr = E + r * 2 * E_EDGES + base;
  for (int i = tid; i < n; i += 256) atomicAdd(&hist[darr[i] >> 7], 1);
  __syncthreads();
  if (tid == 0) {
    int s = 0;
    for (int b = 0; b < nb; b++) { start[b] = s; s += hist[b]; }
  }
  __syncthreads();
  if (tid < nb) {
    gbase[tid] = atomicAdd(&bcur[a.bkoff[slot] + tid], hist[tid]);
    lcur[tid] = start[tid];
  }
  __syncthreads();
  for (int i = tid; i < n; i += 256) {
    int dst = darr[i], src = sarr[i];
    int pos = atomicAdd(&lcur[dst >> 7], 1);
    sorted[pos] = ((u32)dst << 16) | (u32)src;
  }
  __syncthreads();
  u32* out = tmp + (long)slot * E_EDGES;
  for (int i = tid; i < n; i += 256) {
    u32 p = sorted[i];
    int b = p >> 23;
    out[gbase[b] + (i - start[b])] = p;
  }
}

// pass C: per-(slot,bucket): derive rowptr segment + LDS counting-sort into CSR
__global__ __launch_bounds__(256) void bucket_to_csr(const u32* __restrict__ tmp,
                                                     const int* __restrict__ bbase,
                                                     int* __restrict__ rp,
                                                     int* __restrict__ esrc, CsrArgs a)
{
  const int b = blockIdx.x, slot = blockIdx.y;
  if (b >= a.nb[slot]) return;
  const int rb = a.rpoff[slot];
  const int bb = bbase[a.bboff[slot] + b];
  const int be = bbase[a.bboff[slot] + b + 1];
  const int cnt = be - bb;
  const int rowlo = b << 7;
  int rowhi = rowlo + 128; if (rowhi > a.nd[slot]) rowhi = a.nd[slot];
  const int nrow = rowhi - rowlo;
  const int tid = threadIdx.x;
  __shared__ int rcnt[128];
  __shared__ int rpref[129];
  __shared__ int scur[128];
  __shared__ u32 sbuf[8192];
  if (tid < 128) rcnt[tid] = 0;
  __syncthreads();
  const u32* in = tmp + (long)slot * E_EDGES + bb;
  for (int i = tid; i < cnt; i += 256) atomicAdd(&rcnt[(in[i] >> 16) & 127], 1);
  __syncthreads();
  if (tid == 0) {
    int s = 0;
    for (int t = 0; t < 128; t++) { rpref[t] = s; s += rcnt[t]; }
    rpref[128] = s;
  }
  __syncthreads();
  if (tid < nrow) rp[rb + rowlo + tid] = bb + rpref[tid];
  if (tid == 0) rp[rb + rowhi] = be;
  if (tid < 128) scur[tid] = rpref[tid];
  __syncthreads();
  int* out = esrc + (long)slot * E_EDGES + bb;
  if (cnt <= 8192) {
    for (int i = tid; i < cnt; i += 256) {
      u32 p = in[i];
      int pos = atomicAdd(&scur[(p >> 16) & 127], 1);
      sbuf[pos] = p & 0xFFFFu;
    }
    __syncthreads();
    for (int i = tid; i < cnt; i += 256) out[i] = (int)sbuf[i];
  } else {
    for (int i = tid; i < cnt; i += 256) {
      u32 p = in[i];
      int pos = atomicAdd(&scur[(p >> 16) & 127], 1);
      out[pos] = (int)(p & 0xFFFFu);
    }
  }
}

// ---------------- weight prep ----------------
__global__ __launch_bounds__(256) void wtstack_kernel(const float* __restrict__ wl,
                                                      const float* __restrict__ wr,
                                                      const float* __restrict__ bl,
                                                      u16* __restrict__ WTG,
                                                      float* __restrict__ BLS, WTStackArgs a)
{
  int slot = blockIdx.y;
  int t = blockIdx.x * 256 + threadIdx.x;
  int krel = t & 127, n = t >> 7;
  int sr = a.srcrel[slot];
  float v;
  if (sr >= 0) {
    v = wl[(long)sr * 16384 + krel * 128 + n];
  } else {
    int g = a.grp[slot];
    v = 0.f;
    for (int i = 0; i < a.gnr[g]; i++) v += wr[(long)a.grel[g][i] * 16384 + krel * 128 + n];
    if (t < 128) {
      float b = 0.f;
      for (int i = 0; i < a.gnr[g]; i++) b += bl[a.grel[g][i] * 128 + t];
      BLS[g * 128 + t] = b;
    }
  }
  WTG[a.outoff[slot] + (long)n * a.pitch[slot] + a.koff[slot] + krel] = f2bf(v);
}

__global__ __launch_bounds__(256) void wt_kernel(WTArgs a)
{
  int s = blockIdx.y;
  int idx = blockIdx.x * 256 + threadIdx.x;
  int K = a.K[s], N = a.N[s], Kpad = a.Kpad[s];
  if (idx >= N * Kpad) return;
  int n = idx / Kpad, k = idx - n * Kpad;
  a.out[s][idx] = (k < K) ? f2bf(a.W[s][(long)k * N + n]) : (u16)0;
}

__global__ __launch_bounds__(256) void f2b_kernel(F2BArgs a)
{
  int s = blockIdx.y;
  int i = blockIdx.x * 256 + threadIdx.x;
  if (i >= a.n4[s]) return;
  float4 v = ((const float4*)a.s[s])[i];
  ushort4 o; o.x = f2bf(v.x); o.y = f2bf(v.y); o.z = f2bf(v.z); o.w = f2bf(v.w);
  ((ushort4*)a.d[s])[i] = o;
}

__global__ __launch_bounds__(256) void pos_kernel(PosArgs a)
{
  int g = blockIdx.y;
  int i = blockIdx.x * 256 + threadIdx.x;
  if (i >= a.n[g]) return;
  int key = a.m0[g][i];
  const int* m1 = a.m1[g];
  int lo = 0, hi = a.n[g] - 1, pos = -1;
  while (lo <= hi) {
    int mid = (lo + hi) >> 1;
    int v = m1[mid];
    if (v == key) { pos = mid; break; }
    if (v < key) lo = mid + 1; else hi = mid - 1;
  }
  a.pos[g][i] = pos;
}

// ---------------- aggregation ----------------
__global__ __launch_bounds__(256) void agg_kernel(AggArgs a)
{
  int slot = blockIdx.y;
  int wave = threadIdx.x >> 6, lane = threadIdx.x & 63;
  int row = blockIdx.x * 4 + wave;
  if (row >= a.nd) return;
  u16* dst = a.abuf + (long)row * a.pitch + slot * 128 + lane * 2;
  const u32* x2 = (const u32*)a.xsrc[slot];
  if (slot == a.nrels) {
    *(u32*)dst = x2[(long)row * 64 + lane];
    return;
  }
  const int* rp = a.rowptr[slot];
  int c0 = rp[row], c1 = rp[row + 1];
  const int* es = a.esrc[slot];
  float ax = 0.f, ay = 0.f;
  int e = c0;
  for (; e + 4 <= c1; e += 4) {
    int s0 = es[e], s1 = es[e + 1], s2 = es[e + 2], s3 = es[e + 3];
    u32 v0 = x2[(long)s0 * 64 + lane];
    u32 v1 = x2[(long)s1 * 64 + lane];
    u32 v2 = x2[(long)s2 * 64 + lane];
    u32 v3 = x2[(long)s3 * 64 + lane];
    ax += bf2f(v0 & 0xFFFF) + bf2f(v1 & 0xFFFF) + bf2f(v2 & 0xFFFF) + bf2f(v3 & 0xFFFF);
    ay += bf2f(v0 >> 16) + bf2f(v1 >> 16) + bf2f(v2 >> 16) + bf2f(v3 >> 16);
  }
  for (; e < c1; e++) {
    u32 v = x2[(long)es[e] * 64 + lane];
    ax += bf2f(v & 0xFFFF);
    ay += bf2f(v >> 16);
  }
  int c = c1 - c0;
  float inv = 1.f / (float)(c > 1 ? c : 1);
  ax *= inv; ay *= inv;
  *(u32*)dst = (u32)f2bf(ax) | ((u32)f2bf(ay) << 16);
}

// ---------------- batched head reduce ----------------
__global__ __launch_bounds__(64) void head_reduce2(HeadRArgs a)
{
  int row = blockIdx.x;
  int z = blockIdx.y;
  int lane = threadIdx.x;
  const float* h = a.hid[z] + (long)row * 256;
  const float* w2 = a.w2[z];
  float s = h[lane] * w2[lane] + h[lane + 64] * w2[lane + 64]
          + h[lane + 128] * w2[lane + 128] + h[lane + 192] * w2[lane + 192];
  #pragma unroll
  for (int off = 32; off >= 1; off >>= 1) s += __shfl_down(s, off, 64);
  if (lane == 0) {
    float v = s + a.b2[z][0];
    if (z == 0) v = 1.0f / (1.0f + expf(-v));
    a.out[row * 2 + z] = v;
  }
}

// ---------------- host orchestration ----------------
extern "C" void kernel_launch(void* const* d_in, const int* in_sizes, int n_in,
                              void* d_out, int out_size, void* d_ws, size_t ws_size,
                              hipStream_t stream)
{
  static const int NT[6] = {25000, 15000, 4000, 12000, 12000, 15000};
  static const int REL_S[19] = {2,0,2,1,0,1,3,3,1,3,1,3,4,5,0,5,1,0,1};
  static const int REL_D[19] = {0,2,1,2,1,0,3,1,3,1,3,4,3,0,5,1,5,1,0};

  auto xin   = [&](int t, int L) { return (const float*)d_in[L * 13 + 2 * t]; };
  auto mapin = [&](int t, int L) { return (const int*)d_in[L * 13 + 2 * t + 1]; };
  const int* edges0 = (const int*)d_in[12];
  const int* edges1 = (const int*)d_in[25];
  const float* W_in_atac  = (const float*)d_in[26];
  const float* b_in_atac  = (const float*)d_in[27];
  const float* W_in_gene  = (const float*)d_in[28];
  const float* b_in_gene  = (const float*)d_in[29];
  const float* W_in_pname = (const float*)d_in[30];
  const float* b_in_pname = (const float*)d_in[31];
  const float* conv_wl = (const float*)d_in[32];
  const float* conv_bl = (const float*)d_in[33];
  const float* conv_wr = (const float*)d_in[34];
  const float* mlp_w1 = (const float*)d_in[35];
  const float* mlp_b1 = (const float*)d_in[36];
  const float* mlp_w2 = (const float*)d_in[37];
  const float* mlp_b2 = (const float*)d_in[38];
  const float* gd_w1 = (const float*)d_in[39];
  const float* gd_b1 = (const float*)d_in[40];
  const float* gd_w2 = (const float*)d_in[41];
  const float* gd_b2 = (const float*)d_in[42];
  const float* gv_w1 = (const float*)d_in[43];
  const float* gv_b1 = (const float*)d_in[44];
  const float* gv_w2 = (const float*)d_in[45];
  const float* gv_b2 = (const float*)d_in[46];
  float* out = (float*)d_out;

  // ---- workspace carve: fp32, bf16, int sections ----
  float* fp = (float*)d_ws;
  auto takef = [&](size_t n) { float* q = fp; fp += n; return q; };
  float* BLS  = takef(5 * 128);
  float* G1   = takef((size_t)15000 * 128);
  u16* bp = (u16*)fp;
  auto takeb = [&](size_t n) { u16* q = bp; bp += n; return q; };
  u16* XB0[6]; u16* XB1[6];
  XB0[0] = takeb((size_t)25000 * 128);
  XB0[1] = takeb((size_t)15000 * 128);
  XB0[2] = takeb((size_t)4000 * 128);
  XB0[3] = takeb((size_t)12000 * 128);
  XB0[4] = takeb((size_t)12000 * 128);
  XB0[5] = takeb((size_t)15000 * 128);
  XB1[0] = takeb((size_t)25000 * 128);
  XB1[1] = takeb((size_t)15000 * 128);
  XB1[2] = takeb((size_t)4000 * 128);
  XB1[3] = takeb((size_t)12000 * 128);
  XB1[4] = nullptr;
  XB1[5] = takeb((size_t)15000 * 128);
  u16* ABUF = takeb((size_t)16000000);       // >= 25000*640 and 15000*896
  u16* NWB  = takeb((size_t)25000 * 128);
  u16* HIDB = takeb((size_t)25000 * 256);
  u16* WTG  = takeb(376832);
  u16* WTIA = takeb(128 * 288);
  u16* WTIG = takeb(128 * 160);
  u16* WTIP = takeb(128 * 160);
  u16* WTM1 = takeb((size_t)5 * 32768);
  u16* WTM2 = takeb((size_t)5 * 32768);
  u16* WTHD = takeb(32768);
  u16* WTHV = takeb(32768);
  uintptr_t ipa = ((uintptr_t)bp + 15) & ~(uintptr_t)15;
  int* ip = (int*)ipa;
  auto takei = [&](size_t n) { int* q = ip; ip += n; return q; };
  int* RP    = takei(366024);
  int* BCNT  = takei(4704);
  int* BBASE = takei(4728);
  int* BCUR  = takei(4704);
  int* POSB  = takei(71000);
  int* ESRC  = takei((size_t)24 * E_EDGES);
  // aliases (disjoint lifetimes)
  u32* TMP = (u32*)ABUF;
  float* HIDF0 = (float*)ABUF;
  float* HIDF1 = (float*)(ABUF + (size_t)15000 * 256 * 2);

  // dst-type groups
  static const int GD[5]       = {0, 1, 2, 3, 5};
  static const int GNR[5]      = {4, 6, 2, 4, 2};
  static const int GRELS[5][6] = {{0,5,13,18,0,0},{2,4,7,9,15,17},{1,3,0,0,0,0},
                                  {6,8,10,12,0,0},{14,16,0,0,0,0}};
  static const int GPITCH[5]   = {640, 896, 384, 640, 384};
  long gbaseT[5];
  {
    long o = 0;
    for (int g = 0; g < 5; g++) { gbaseT[g] = o; o += (long)128 * GPITCH[g]; }
  }
  int* POSg[5];
  {
    int o = 0;
    for (int g = 0; g < 5; g++) { POSg[g] = POSB + o; o += NT[GD[g]]; }
  }

  // 1) weight prep + POS permutation
  {
    WTStackArgs wa{};
    int j = 0;
    for (int g = 0; g < 5; g++) {
      wa.gnr[g] = GNR[g];
      for (int i = 0; i < 6; i++) wa.grel[g][i] = GRELS[g][i];
      for (int s = 0; s <= GNR[g]; s++, j++) {
        wa.srcrel[j] = (s < GNR[g]) ? GRELS[g][s] : -1;
        wa.grp[j] = g;
        wa.outoff[j] = gbaseT[g];
        wa.koff[j] = s * 128;
        wa.pitch[j] = GPITCH[g];
      }
    }
    hipLaunchKernelGGL(wtstack_kernel, dim3(64, 23), dim3(256), 0, stream,
                       conv_wl, conv_wr, conv_bl, WTG, BLS, wa);
  }
  {
    WTArgs pa{};
    int s = 0;
    auto add = [&](const float* W, u16* o, int K, int N, int Kpad) {
      pa.W[s] = W; pa.out[s] = o; pa.K[s] = K; pa.N[s] = N; pa.Kpad[s] = Kpad; s++;
    };
    add(W_in_atac,  WTIA, 257, 128, 288);
    add(W_in_gene,  WTIG, 129, 128, 160);
    add(W_in_pname, WTIP, 129, 128, 160);
    for (int g = 0; g < 5; g++) {
      int d = GD[g];
      add(mlp_w1 + (long)d * 128 * 256, WTM1 + (long)g * 32768, 128, 256, 128);
      add(mlp_w2 + (long)d * 256 * 128, WTM2 + (long)g * 32768, 256, 128, 256);
    }
    add(gd_w1, WTHD, 128, 256, 128);
    add(gv_w1, WTHV, 128, 256, 128);
    hipLaunchKernelGGL(wt_kernel, dim3(144, 15), dim3(256), 0, stream, pa);
  }
  {
    PosArgs pa{};
    for (int g = 0; g < 5; g++) {
      int d = GD[g];
      pa.m0[g] = mapin(d, 0); pa.m1[g] = mapin(d, 1); pa.pos[g] = POSg[g]; pa.n[g] = NT[d];
    }
    hipLaunchKernelGGL(pos_kernel, dim3(98, 5), dim3(256), 0, stream, pa);
  }

  auto mg = [&](int af32, int of32, int relu, const void* A, const u16* WT,
                const float* b, void* C, int M, int K, int Kpad, int N) {
    dim3 grid((M + 63) / 64, N / 128);
    if (af32) {
      hipLaunchKernelGGL(HIP_KERNEL_NAME(tgemm<1,0,0>), grid, dim3(256), 0, stream, A, WT, b, C, M, K, Kpad, N);
    } else {
      if (of32)      hipLaunchKernelGGL(HIP_KERNEL_NAME(tgemm<0,1,0>), grid, dim3(256), 0, stream, A, WT, b, C, M, K, Kpad, N);
      else if (relu) hipLaunchKernelGGL(HIP_KERNEL_NAME(tgemm<0,0,1>), grid, dim3(256), 0, stream, A, WT, b, C, M, K, Kpad, N);
      else           hipLaunchKernelGGL(HIP_KERNEL_NAME(tgemm<0,0,0>), grid, dim3(256), 0, stream, A, WT, b, C, M, K, Kpad, N);
    }
  };

  // 2) input linears (batched) + raw-table converts (batched)
  {
    InLinArgs ia{};
    auto add = [&](int s, const float* A, const u16* WT, const float* b, u16* C,
                   int M, int K, int Kpad) {
      ia.A[s] = A; ia.WT[s] = WT; ia.bias[s] = b; ia.C[s] = C;
      ia.M[s] = M; ia.K[s] = K; ia.Kpad[s] = Kpad;
    };
    add(0, xin(0,0), WTIA, b_in_atac,  XB0[0], 25000, 257, 288);
    add(1, xin(1,0), WTIG, b_in_gene,  XB0[1], 15000, 129, 160);
    add(2, xin(4,0), WTIP, b_in_pname, XB0[4], 12000, 129, 160);
    add(3, xin(0,1), WTIA, b_in_atac,  XB1[0], 25000, 257, 288);
    add(4, xin(1,1), WTIG, b_in_gene,  XB1[1], 15000, 129, 160);
    hipLaunchKernelGGL(tgemm_in, dim3(391, 1, 5), dim3(256), 0, stream, ia);
  }
  {
    F2BArgs fa{};
    const float* ss[6] = {xin(2,0), xin(3,0), xin(5,0), xin(2,1), xin(3,1), xin(5,1)};
    u16* dd[6] = {XB0[2], XB0[3], XB0[5], XB1[2], XB1[3], XB1[5]};
    int nn[6] = {4000*32, 12000*32, 15000*32, 4000*32, 12000*32, 15000*32};
    for (int s = 0; s < 6; s++) { fa.s[s] = ss[s]; fa.d[s] = dd[s]; fa.n4[s] = nn[s]; }
    hipLaunchKernelGGL(f2b_kernel, dim3(1875, 6), dim3(256), 0, stream, fa);
  }

  // 3) CSR build (combined L0 18 + L1 6 slots): bucket hist -> scan -> scatter -> csr
  static const int L0R[18] = {0,1,2,3,4,5,6,7,8,9,10,12,13,14,15,16,17,18};
  static const int L1R[6]  = {2, 4, 7, 9, 15, 17};
  int rpoffByRel[19], slotByRel[19], rpoff1[19], slot1[19];
  CsrArgs cc{};
  {
    int ro = 0, bo = 0, s = 0;
    for (int i = 0; i < 18; i++, s++) {
      int r = L0R[i];
      cc.relid[s] = r; cc.lay[s] = 0; int nd = NT[REL_D[r]];
      cc.nd[s] = nd; cc.rpoff[s] = ro;
      cc.bkoff[s] = bo; cc.bboff[s] = bo + s; cc.nb[s] = (nd + 127) >> 7;
      rpoffByRel[r] = ro; slotByRel[r] = s;
      ro += nd + 1; bo += cc.nb[s];
    }
    for (int i = 0; i < 6; i++, s++) {
      int r = L1R[i];
      cc.relid[s] = r; cc.lay[s] = 1;
      cc.nd[s] = 15000; cc.rpoff[s] = ro;
      cc.bkoff[s] = bo; cc.bboff[s] = bo + s; cc.nb[s] = (15000 + 127) >> 7;
      rpoff1[r] = ro; slot1[r] = s;
      ro += 15001; bo += cc.nb[s];
    }
    hipMemsetAsync(BCNT, 0, (size_t)bo * 4, stream);
    hipLaunchKernelGGL(bhist_kernel, dim3(24 * 25), dim3(256), 0, stream, edges0, edges1, BCNT, cc);
    hipLaunchKernelGGL(bscan_kernel, dim3(24), dim3(256), 0, stream, BCNT, BBASE, BCUR, cc);
    hipLaunchKernelGGL(bucket_scatter, dim3(24 * 25), dim3(256), 0, stream,
                       edges0, edges1, BCUR, TMP, cc);
    hipLaunchKernelGGL(bucket_to_csr, dim3(196, 24), dim3(256), 0, stream, TMP, BBASE, RP, ESRC, cc);
  }

  // 4) per dst group: aggregate -> conv GEMM -> MLP1 -> MLP2+scatter
  for (int g = 0; g < 5; g++) {
    int d = GD[g];
    AggArgs aa{};
    aa.nrels = GNR[g]; aa.nd = NT[d]; aa.pitch = GPITCH[g]; aa.abuf = ABUF;
    for (int i = 0; i < GNR[g]; i++) {
      int r = GRELS[g][i];
      aa.xsrc[i]   = XB0[REL_S[r]];
      aa.rowptr[i] = RP + rpoffByRel[r];
      aa.esrc[i]   = ESRC + (long)slotByRel[r] * E_EDGES;
    }
    aa.xsrc[GNR[g]] = XB0[d];
    hipLaunchKernelGGL(agg_kernel, dim3((NT[d] + 3) / 4, GNR[g] + 1), dim3(256), 0, stream, aa);
    mg(0,0,0, ABUF, WTG + gbaseT[g], BLS + g * 128, NWB, NT[d], GPITCH[g], GPITCH[g], 128);
    mg(0,0,1, NWB,  WTM1 + (long)g * 32768, mlp_b1 + d * 256, HIDB, NT[d], 128, 128, 256);
    hipLaunchKernelGGL(tgemm_scat, dim3((NT[d] + 63) / 64), dim3(256), 0, stream,
                       HIDB, WTM2 + (long)g * 32768, mlp_b2 + d * 128, POSg[g],
                       XB1[d], NT[d], 256);
  }

  // 5) layer-1 gene conv: aggregate + GEMM -> G1 (fp32)
  {
    AggArgs aa{};
    aa.nrels = 6; aa.nd = 15000; aa.pitch = 896; aa.abuf = ABUF;
    for (int i = 0; i < 6; i++) {
      int r = L1R[i];
      aa.xsrc[i]   = XB1[REL_S[r]];
      aa.rowptr[i] = RP + rpoff1[r];
      aa.esrc[i]   = ESRC + (long)slot1[r] * E_EDGES;
    }
    aa.xsrc[6] = XB1[1];
    hipLaunchKernelGGL(agg_kernel, dim3((15000 + 3) / 4, 7), dim3(256), 0, stream, aa);
    mg(0,1,0, ABUF, WTG + gbaseT[1], BLS + 1 * 128, G1, 15000, 896, 896, 128);
  }

  // 6) gene heads: batched MFMA (z=2) + batched reduce
  {
    HeadArgs ha{};
    ha.WT[0] = WTHD; ha.WT[1] = WTHV;
    ha.b1[0] = gd_b1; ha.b1[1] = gv_b1;
    ha.hid[0] = HIDF0; ha.hid[1] = HIDF1;
    ha.A = G1; ha.M = 15000;
    hipLaunchKernelGGL(tgemm_head, dim3(235, 2, 2), dim3(256), 0, stream, ha);
    HeadRArgs hr{};
    hr.hid[0] = HIDF0; hr.hid[1] = HIDF1;
    hr.w2[0] = gd_w2; hr.w2[1] = gv_w2;
    hr.b2[0] = gd_b2; hr.b2[1] = gv_b2;
    hr.out = out;
    hipLaunchKernelGGL(head_reduce2, dim3(15000, 2), dim3(64), 0, stream, hr);
  }
}